// Round 1
// baseline (474.163 us; speedup 1.0000x reference)
//
#include <hip/hip_runtime.h>
#include <hip/hip_bf16.h>

#define NFFT 8192
#define TPB  256
#define VPT  32   // NFFT / TPB

// XOR swizzle at float2 granularity: spreads all strided FFT access patterns
// across the 32 LDS banks. Involution (only low 4 bits change).
__device__ __forceinline__ int swz(int j) { return j ^ ((j >> 4) & 15); }
__device__ __forceinline__ int rev13(unsigned x) { return (int)(__brev(x) >> 19); }

__device__ __forceinline__ float2 cadd(float2 a, float2 b){ return make_float2(a.x+b.x, a.y+b.y); }
__device__ __forceinline__ float2 csub(float2 a, float2 b){ return make_float2(a.x-b.x, a.y-b.y); }
// d * (c - i s)  (forward twiddle)
__device__ __forceinline__ float2 cmul_conj(float2 d, float c, float s){
  return make_float2(d.x*c + d.y*s, d.y*c - d.x*s);
}
// v * (c + i s)  (inverse twiddle)
__device__ __forceinline__ float2 cmul_pos(float2 v, float c, float s){
  return make_float2(v.x*c - v.y*s, v.y*c + v.x*s);
}

// Twiddles for a fused-3 round: one sincos, rest by double-angle / pi/4 rotations.
// alpha = p*pi/(4S);  A_k = alpha + k*pi/4 (k=0..3), B_k0 = 2a + k0*pi/2, C = 4a.
template<int S>
__device__ __forceinline__ void make_tw(int p, float* cA, float* sA,
                                        float* cB, float* sB, float& c4, float& s4) {
  float a = (float)p * (0.78539816339744831f / (float)S);
  float sa, ca;
  __sincosf(a, &sa, &ca);
  float c2 = ca*ca - sa*sa, s2 = 2.0f*ca*sa;
  c4 = c2*c2 - s2*s2; s4 = 2.0f*c2*s2;
  const float R = 0.70710678118654752f;
  cA[0] = ca;          sA[0] = sa;
  cA[1] = R*(ca-sa);   sA[1] = R*(ca+sa);
  cA[2] = -sa;         sA[2] = ca;
  cA[3] = -R*(ca+sa);  sA[3] = R*(ca-sa);
  cB[0] = c2;  sB[0] = s2;
  cB[1] = -s2; sB[1] = c2;
}

// Forward DIF fused round: spans 4S, 2S, S. Blocks of 8S, 8 points/group stride S.
template<int S>
__device__ __forceinline__ void dif_round(float2* z, int t) {
  #pragma unroll
  for (int gi = 0; gi < 4; ++gi) {
    int g = t + TPB*gi;
    int p = g & (S-1);
    int blk = g / S;
    int base = blk*(8*S) + p;
    float2 y[8];
    #pragma unroll
    for (int k = 0; k < 8; ++k) y[k] = z[swz(base + k*S)];
    float cA[4], sA[4], cB[2], sB[2], c4, s4;
    make_tw<S>(p, cA, sA, cB, sB, c4, s4);
    // stage span 4S: pairs (k,k+4), twiddle A_k on (u-v)
    #pragma unroll
    for (int k = 0; k < 4; ++k) {
      float2 u = y[k], v = y[k+4];
      y[k] = cadd(u,v);
      y[k+4] = cmul_conj(csub(u,v), cA[k], sA[k]);
    }
    // stage span 2S: pairs (h+k0, h+k0+2), twiddle B_k0
    #pragma unroll
    for (int h = 0; h < 8; h += 4)
      #pragma unroll
      for (int k0 = 0; k0 < 2; ++k0) {
        float2 u = y[h+k0], v = y[h+k0+2];
        y[h+k0] = cadd(u,v);
        y[h+k0+2] = cmul_conj(csub(u,v), cB[k0], sB[k0]);
      }
    // stage span S: pairs (h,h+1), twiddle C
    #pragma unroll
    for (int h = 0; h < 8; h += 2) {
      float2 u = y[h], v = y[h+1];
      y[h] = cadd(u,v);
      y[h+1] = cmul_conj(csub(u,v), c4, s4);
    }
    #pragma unroll
    for (int k = 0; k < 8; ++k) z[swz(base + k*S)] = y[k];
  }
  __syncthreads();
}

// Inverse DIT fused round: spans S, 2S, 4S (conjugate twiddles, applied to v before add).
template<int S>
__device__ __forceinline__ void dit_round(float2* z, int t) {
  #pragma unroll
  for (int gi = 0; gi < 4; ++gi) {
    int g = t + TPB*gi;
    int p = g & (S-1);
    int blk = g / S;
    int base = blk*(8*S) + p;
    float2 y[8];
    #pragma unroll
    for (int k = 0; k < 8; ++k) y[k] = z[swz(base + k*S)];
    float cA[4], sA[4], cB[2], sB[2], c4, s4;
    make_tw<S>(p, cA, sA, cB, sB, c4, s4);
    // stage span S
    #pragma unroll
    for (int h = 0; h < 8; h += 2) {
      float2 u = y[h];
      float2 w = cmul_pos(y[h+1], c4, s4);
      y[h] = cadd(u,w); y[h+1] = csub(u,w);
    }
    // stage span 2S
    #pragma unroll
    for (int h = 0; h < 8; h += 4)
      #pragma unroll
      for (int k0 = 0; k0 < 2; ++k0) {
        float2 u = y[h+k0];
        float2 w = cmul_pos(y[h+k0+2], cB[k0], sB[k0]);
        y[h+k0] = cadd(u,w); y[h+k0+2] = csub(u,w);
      }
    // stage span 4S
    #pragma unroll
    for (int k = 0; k < 4; ++k) {
      float2 u = y[k];
      float2 w = cmul_pos(y[k+4], cA[k], sA[k]);
      y[k] = cadd(u,w); y[k+4] = csub(u,w);
    }
    #pragma unroll
    for (int k = 0; k < 8; ++k) z[swz(base + k*S)] = y[k];
  }
  __syncthreads();
}

// Twiddle-free span-1 stage (fwd last / inv first): pairs (2i, 2i+1).
__device__ __forceinline__ void span1(float2* z, int t) {
  #pragma unroll
  for (int gi = 0; gi < 16; ++gi) {
    int i = t + TPB*gi;
    int j0 = swz(2*i), j1 = swz(2*i+1);
    float2 u = z[j0], v = z[j1];
    z[j0] = cadd(u,v); z[j1] = csub(u,v);
  }
  __syncthreads();
}

__global__ __launch_bounds__(TPB, 2)
void corr_align_kernel(const float* __restrict__ x, const float* __restrict__ xref,
                       float* __restrict__ out0, float* __restrict__ outInd) {
  __shared__ float2 z[NFFT];   // exactly 64 KiB
  const int t = threadIdx.x;
  const int row = blockIdx.x;
  const float* xrow = x + (size_t)row * NFFT;
  const float* rrow = xref + (size_t)row * NFFT;

  // ---- load: z[n] = x[n] + i*xref[n] (two real FFTs for the price of one) ----
  const float4* x4 = (const float4*)xrow;
  const float4* r4 = (const float4*)rrow;
  #pragma unroll
  for (int gi = 0; gi < 8; ++gi) {
    int q = t + TPB*gi;
    float4 xv = x4[q], rv = r4[q];
    int j = 4*q;
    z[swz(j+0)] = make_float2(xv.x, rv.x);
    z[swz(j+1)] = make_float2(xv.y, rv.y);
    z[swz(j+2)] = make_float2(xv.z, rv.z);
    z[swz(j+3)] = make_float2(xv.w, rv.w);
  }
  __syncthreads();

  // ---- forward DIF FFT: natural -> bit-reversed ----
  dif_round<1024>(z, t);
  dif_round<128>(z, t);
  dif_round<16>(z, t);
  dif_round<2>(z, t);
  span1(z, t);

  // ---- unpack X,Y from Z (conjugate symmetry) and form G = conj(X)*Y ----
  // Position p holds frequency k=rev13(p); freq -k lives at position rev13(N-k).
  float2 G[VPT];
  #pragma unroll
  for (int gi = 0; gi < VPT; ++gi) {
    int p = t + TPB*gi;
    int k = rev13((unsigned)p);
    int q = rev13((unsigned)((NFFT - k) & (NFFT-1)));
    float2 Zp = z[swz(p)];
    float2 Zq = z[swz(q)];
    float Xx = 0.5f*(Zp.x + Zq.x);
    float Xy = 0.5f*(Zp.y - Zq.y);
    float Yx = 0.5f*(Zp.y + Zq.y);
    float Yy = 0.5f*(Zq.x - Zp.x);
    G[gi] = make_float2(Xx*Yx + Xy*Yy, Xx*Yy - Xy*Yx);
  }
  __syncthreads();   // all reads done before any write (p<->q cross-thread)
  #pragma unroll
  for (int gi = 0; gi < VPT; ++gi) z[swz(t + TPB*gi)] = G[gi];
  __syncthreads();

  // ---- inverse DIT FFT: bit-reversed -> natural; z[swz(j)].x = N*corr[j] ----
  span1(z, t);
  dit_round<2>(z, t);
  dit_round<16>(z, t);
  dit_round<128>(z, t);
  dit_round<1024>(z, t);

  // ---- argmax with fp64 refinement (np reference uses float64 FFT) ----
  float* zf = (float*)z;
  int* cnt = (int*)&zf[11];        // z[5].y: candidate counter (junk imag slot)
  if (t == 0) *cnt = 0;
  float mv = -3.0e38f;
  #pragma unroll
  for (int gi = 0; gi < VPT; ++gi) {
    int j = t + TPB*gi;
    mv = fmaxf(mv, z[swz(j)].x);
  }
  #pragma unroll
  for (int off = 32; off > 0; off >>= 1)
    mv = fmaxf(mv, __shfl_down(mv, off));
  const int lane = t & 63, wave = t >> 6;
  if (lane == 0) zf[2*wave + 1] = mv;   // z[wave].y
  __syncthreads();
  float M = fmaxf(fmaxf(zf[1], zf[3]), fmaxf(zf[5], zf[7]));
  // margin 4.0 in corr units = 32768 raw (>>100x the f32 FFT error bound)
  float thresh = M - 32768.0f;
  #pragma unroll
  for (int gi = 0; gi < VPT; ++gi) {
    int j = t + TPB*gi;
    if (z[swz(j)].x >= thresh) {
      int slot = atomicAdd(cnt, 1);
      if (slot < 40) zf[2*(8+slot)+1] = (float)j;   // z[8+slot].y
    }
  }
  __syncthreads();
  int count = *cnt;
  if (count > 40) count = 40;

  int bestPos;
  if (count == 1) {
    // unique candidate within margin => exact argmax (error << margin/2)
    bestPos = (int)zf[2*8+1];
  } else {
    double bestV = -1.0e300;
    int bp = NFFT;
    for (int c = 0; c < count; ++c) {
      int pos = (int)zf[2*(8+c)+1];
      double part = 0.0;
      #pragma unroll
      for (int gi = 0; gi < VPT; ++gi) {
        int n = t + TPB*gi;
        part += (double)xrow[n] * (double)rrow[(n + pos) & (NFFT-1)];
      }
      #pragma unroll
      for (int off = 32; off > 0; off >>= 1)
        part += __shfl_down(part, off);
      if (lane == 0) *((double*)&zf[2*(64 + 2*wave)]) = part;  // z[64..70], corr dead
      __syncthreads();
      if (t == 0) {
        double tot = 0.0;
        #pragma unroll
        for (int w = 0; w < 4; ++w) tot += *((double*)&zf[2*(64 + 2*w)]);
        if (tot > bestV || (tot == bestV && pos < bp)) { bestV = tot; bp = pos; }
      }
      __syncthreads();
    }
    if (t == 0) zf[0] = (float)bp;
    __syncthreads();
    bestPos = (int)zf[0];
  }

  // ---- outputs: x_aligned[k] = x[(k - ind) mod N]; inds as float ----
  float* orow = out0 + (size_t)row * NFFT;
  #pragma unroll
  for (int gi = 0; gi < VPT; ++gi) {
    int kk = t + TPB*gi;
    orow[kk] = xrow[(kk - bestPos) & (NFFT-1)];
  }
  if (t == 0) outInd[row] = (float)bestPos;
}

extern "C" void kernel_launch(void* const* d_in, const int* in_sizes, int n_in,
                              void* d_out, int out_size, void* d_ws, size_t ws_size,
                              hipStream_t stream) {
  const float* x    = (const float*)d_in[0];
  const float* xref = (const float*)d_in[1];
  float* out = (float*)d_out;
  const int rows = in_sizes[0] / NFFT;   // 32*64 = 2048
  float* outInd = out + (size_t)rows * NFFT;
  hipLaunchKernelGGL(corr_align_kernel, dim3(rows), dim3(TPB), 0, stream,
                     x, xref, out, outInd);
}

// Round 2
// 304.273 us; speedup vs baseline: 1.5584x; 1.5584x over previous
//
#include <hip/hip_runtime.h>
#include <hip/hip_bf16.h>

#define NFFT 8192
#define TPB  512
#define VPT  16   // NFFT / TPB

// XOR swizzle at float2 granularity: spreads all strided FFT access patterns
// across the 32 LDS banks (b64 accesses land 4 lanes/bank-pair = the wave64 floor).
__device__ __forceinline__ int swz(int j) { return j ^ ((j >> 4) & 15); }
__device__ __forceinline__ int rev13(unsigned x) { return (int)(__brev(x) >> 19); }

__device__ __forceinline__ float2 cadd(float2 a, float2 b){ return make_float2(a.x+b.x, a.y+b.y); }
__device__ __forceinline__ float2 csub(float2 a, float2 b){ return make_float2(a.x-b.x, a.y-b.y); }
// d * (c - i s)  (forward twiddle)
__device__ __forceinline__ float2 cmul_conj(float2 d, float c, float s){
  return make_float2(d.x*c + d.y*s, d.y*c - d.x*s);
}
// v * (c + i s)  (inverse twiddle)
__device__ __forceinline__ float2 cmul_pos(float2 v, float c, float s){
  return make_float2(v.x*c - v.y*s, v.y*c + v.x*s);
}

// Twiddles for a fused radix-8 round. One hw sin + one hw cos (input in
// REVOLUTIONS: v_sin_f32 computes sin(2*pi*x)) — no pointer-output lib call,
// no scratch. alpha = p*pi/(4S); A_k = alpha + k*pi/4; B_k0 = 2a + k0*pi/2; C = 4a.
template<int S>
__device__ __forceinline__ void make_tw(int p, float* cA, float* sA,
                                        float* cB, float* sB, float& c4, float& s4) {
  float r = (float)p * (0.125f / (float)S);   // revolutions: 2*pi*r = p*pi/(4S)
  float sa = __builtin_amdgcn_sinf(r);
  float ca = __builtin_amdgcn_cosf(r);
  float c2 = ca*ca - sa*sa, s2 = 2.0f*ca*sa;
  c4 = c2*c2 - s2*s2; s4 = 2.0f*c2*s2;
  const float R = 0.70710678118654752f;
  cA[0] = ca;          sA[0] = sa;
  cA[1] = R*(ca-sa);   sA[1] = R*(ca+sa);
  cA[2] = -sa;         sA[2] = ca;
  cA[3] = -R*(ca+sa);  sA[3] = R*(ca-sa);
  cB[0] = c2;  sB[0] = s2;
  cB[1] = -s2; sB[1] = c2;
}

// Forward DIF fused radix-8 round: spans 4S,2S,S. 1024 groups, 2 per thread.
template<int S>
__device__ __forceinline__ void dif_round(float2* z, int t) {
  #pragma unroll
  for (int gi = 0; gi < 2; ++gi) {
    int g = t + TPB*gi;
    int p = g & (S-1);
    int blk = g / S;
    int base = blk*(8*S) + p;
    float2 y[8];
    #pragma unroll
    for (int k = 0; k < 8; ++k) y[k] = z[swz(base + k*S)];
    float cA[4], sA[4], cB[2], sB[2], c4, s4;
    make_tw<S>(p, cA, sA, cB, sB, c4, s4);
    #pragma unroll
    for (int k = 0; k < 4; ++k) {
      float2 u = y[k], v = y[k+4];
      y[k] = cadd(u,v);
      y[k+4] = cmul_conj(csub(u,v), cA[k], sA[k]);
    }
    #pragma unroll
    for (int h = 0; h < 8; h += 4)
      #pragma unroll
      for (int k0 = 0; k0 < 2; ++k0) {
        float2 u = y[h+k0], v = y[h+k0+2];
        y[h+k0] = cadd(u,v);
        y[h+k0+2] = cmul_conj(csub(u,v), cB[k0], sB[k0]);
      }
    #pragma unroll
    for (int h = 0; h < 8; h += 2) {
      float2 u = y[h], v = y[h+1];
      y[h] = cadd(u,v);
      y[h+1] = cmul_conj(csub(u,v), c4, s4);
    }
    #pragma unroll
    for (int k = 0; k < 8; ++k) z[swz(base + k*S)] = y[k];
  }
  __syncthreads();
}

// Inverse DIT fused radix-8 round: spans S,2S,4S.
template<int S>
__device__ __forceinline__ void dit_round(float2* z, int t) {
  #pragma unroll
  for (int gi = 0; gi < 2; ++gi) {
    int g = t + TPB*gi;
    int p = g & (S-1);
    int blk = g / S;
    int base = blk*(8*S) + p;
    float2 y[8];
    #pragma unroll
    for (int k = 0; k < 8; ++k) y[k] = z[swz(base + k*S)];
    float cA[4], sA[4], cB[2], sB[2], c4, s4;
    make_tw<S>(p, cA, sA, cB, sB, c4, s4);
    #pragma unroll
    for (int h = 0; h < 8; h += 2) {
      float2 u = y[h];
      float2 w = cmul_pos(y[h+1], c4, s4);
      y[h] = cadd(u,w); y[h+1] = csub(u,w);
    }
    #pragma unroll
    for (int h = 0; h < 8; h += 4)
      #pragma unroll
      for (int k0 = 0; k0 < 2; ++k0) {
        float2 u = y[h+k0];
        float2 w = cmul_pos(y[h+k0+2], cB[k0], sB[k0]);
        y[h+k0] = cadd(u,w); y[h+k0+2] = csub(u,w);
      }
    #pragma unroll
    for (int k = 0; k < 4; ++k) {
      float2 u = y[k];
      float2 w = cmul_pos(y[k+4], cA[k], sA[k]);
      y[k] = cadd(u,w); y[k+4] = csub(u,w);
    }
    #pragma unroll
    for (int k = 0; k < 8; ++k) z[swz(base + k*S)] = y[k];
  }
  __syncthreads();
}

#define C16_1 0.92387953251128674f
#define S16_1 0.38268343236508978f
#define RSQ2  0.70710678118654752f

// Forward radix-16 const-twiddle round: spans 8,4,2,1 on contiguous 16-blocks.
// Angles are j*pi/8 — all compile-time constants, zero transcendentals.
__device__ __forceinline__ void dif16(float2* z, int t) {
  const float C8[8] = {1.f, C16_1, RSQ2, S16_1, 0.f, -S16_1, -RSQ2, -C16_1};
  const float S8[8] = {0.f, S16_1, RSQ2, C16_1, 1.f,  C16_1,  RSQ2,  S16_1};
  float2 y[16];
  int base = 16*t;
  #pragma unroll
  for (int k = 0; k < 16; ++k) y[k] = z[swz(base+k)];
  #pragma unroll
  for (int j = 0; j < 8; ++j) {          // span 8, twiddle W_16^j
    float2 u = y[j], v = y[j+8];
    y[j] = cadd(u,v);
    y[j+8] = cmul_conj(csub(u,v), C8[j], S8[j]);
  }
  #pragma unroll
  for (int h = 0; h < 16; h += 8)        // span 4, twiddle W_8^j
    #pragma unroll
    for (int j = 0; j < 4; ++j) {
      float2 u = y[h+j], v = y[h+j+4];
      y[h+j] = cadd(u,v);
      y[h+j+4] = cmul_conj(csub(u,v), C8[2*j], S8[2*j]);
    }
  #pragma unroll
  for (int h = 0; h < 16; h += 4)        // span 2, twiddle W_4^j (1, -i)
    #pragma unroll
    for (int j = 0; j < 2; ++j) {
      float2 u = y[h+j], v = y[h+j+2];
      y[h+j] = cadd(u,v);
      float2 d = csub(u,v);
      y[h+j+2] = j ? make_float2(d.y, -d.x) : d;
    }
  #pragma unroll
  for (int h = 0; h < 16; h += 2) {      // span 1
    float2 u = y[h], v = y[h+1];
    y[h] = cadd(u,v); y[h+1] = csub(u,v);
  }
  #pragma unroll
  for (int k = 0; k < 16; ++k) z[swz(base+k)] = y[k];
  __syncthreads();
}

// Inverse radix-16 const-twiddle round: spans 1,2,4,8 (conjugate twiddles).
__device__ __forceinline__ void dit16(float2* z, int t) {
  const float C8[8] = {1.f, C16_1, RSQ2, S16_1, 0.f, -S16_1, -RSQ2, -C16_1};
  const float S8[8] = {0.f, S16_1, RSQ2, C16_1, 1.f,  C16_1,  RSQ2,  S16_1};
  float2 y[16];
  int base = 16*t;
  #pragma unroll
  for (int k = 0; k < 16; ++k) y[k] = z[swz(base+k)];
  #pragma unroll
  for (int h = 0; h < 16; h += 2) {      // span 1
    float2 u = y[h], w = y[h+1];
    y[h] = cadd(u,w); y[h+1] = csub(u,w);
  }
  #pragma unroll
  for (int h = 0; h < 16; h += 4)        // span 2, twiddle (1, +i)
    #pragma unroll
    for (int j = 0; j < 2; ++j) {
      float2 u = y[h+j];
      float2 v = y[h+j+2];
      float2 w = j ? make_float2(-v.y, v.x) : v;
      y[h+j] = cadd(u,w); y[h+j+2] = csub(u,w);
    }
  #pragma unroll
  for (int h = 0; h < 16; h += 8)        // span 4
    #pragma unroll
    for (int j = 0; j < 4; ++j) {
      float2 u = y[h+j];
      float2 w = cmul_pos(y[h+j+4], C8[2*j], S8[2*j]);
      y[h+j] = cadd(u,w); y[h+j+4] = csub(u,w);
    }
  #pragma unroll
  for (int j = 0; j < 8; ++j) {          // span 8
    float2 u = y[j];
    float2 w = cmul_pos(y[j+8], C8[j], S8[j]);
    y[j] = cadd(u,w); y[j+8] = csub(u,w);
  }
  #pragma unroll
  for (int k = 0; k < 16; ++k) z[swz(base+k)] = y[k];
  __syncthreads();
}

// Last inverse round (S=1024, spans 1024,2048,4096): keep results in registers,
// fold in the local max. NO LDS write-back, no trailing barrier (caller syncs).
__device__ __forceinline__ void dit_last(const float2* z, int t, float* re, float& mv) {
  #pragma unroll
  for (int gi = 0; gi < 2; ++gi) {
    const int S = 1024;
    int g = t + TPB*gi;          // = p; blk is always 0 (8S == NFFT)
    int base = g;
    float2 y[8];
    #pragma unroll
    for (int k = 0; k < 8; ++k) y[k] = z[swz(base + k*S)];
    float cA[4], sA[4], cB[2], sB[2], c4, s4;
    make_tw<S>(g, cA, sA, cB, sB, c4, s4);
    #pragma unroll
    for (int h = 0; h < 8; h += 2) {
      float2 u = y[h];
      float2 w = cmul_pos(y[h+1], c4, s4);
      y[h] = cadd(u,w); y[h+1] = csub(u,w);
    }
    #pragma unroll
    for (int h = 0; h < 8; h += 4)
      #pragma unroll
      for (int k0 = 0; k0 < 2; ++k0) {
        float2 u = y[h+k0];
        float2 w = cmul_pos(y[h+k0+2], cB[k0], sB[k0]);
        y[h+k0] = cadd(u,w); y[h+k0+2] = csub(u,w);
      }
    #pragma unroll
    for (int k = 0; k < 4; ++k) {
      float2 u = y[k];
      float2 w = cmul_pos(y[k+4], cA[k], sA[k]);
      y[k] = cadd(u,w); y[k+4] = csub(u,w);
    }
    #pragma unroll
    for (int k = 0; k < 8; ++k) {
      re[8*gi + k] = y[k].x;     // corr*N at position g + 1024*k (natural order)
      mv = fmaxf(mv, y[k].x);
    }
  }
}

__global__ __launch_bounds__(TPB, 4)
void corr_align_kernel(const float* __restrict__ x, const float* __restrict__ xref,
                       float* __restrict__ out0, float* __restrict__ outInd) {
  __shared__ float2 z[NFFT];   // exactly 64 KiB -> 2 blocks/CU, 16 waves/CU
  const int t = threadIdx.x;
  const int row = blockIdx.x;
  const float* xrow = x + (size_t)row * NFFT;
  const float* rrow = xref + (size_t)row * NFFT;

  // ---- load: z[n] = x[n] + i*xref[n] ----
  const float4* x4 = (const float4*)xrow;
  const float4* r4 = (const float4*)rrow;
  #pragma unroll
  for (int gi = 0; gi < 4; ++gi) {
    int q = t + TPB*gi;
    float4 xv = x4[q], rv = r4[q];
    int j = 4*q;
    z[swz(j+0)] = make_float2(xv.x, rv.x);
    z[swz(j+1)] = make_float2(xv.y, rv.y);
    z[swz(j+2)] = make_float2(xv.z, rv.z);
    z[swz(j+3)] = make_float2(xv.w, rv.w);
  }
  __syncthreads();

  // ---- forward DIF FFT: natural -> bit-reversed ----
  dif_round<1024>(z, t);
  dif_round<128>(z, t);
  dif_round<16>(z, t);
  dif16(z, t);

  // ---- unpack X,Y (conjugate symmetry), form G = conj(X)*Y ----
  float2 G[VPT];
  #pragma unroll
  for (int gi = 0; gi < VPT; ++gi) {
    int p = t + TPB*gi;
    int k = rev13((unsigned)p);
    int q = rev13((unsigned)((NFFT - k) & (NFFT-1)));
    float2 Zp = z[swz(p)];
    float2 Zq = z[swz(q)];
    float Xx = 0.5f*(Zp.x + Zq.x);
    float Xy = 0.5f*(Zp.y - Zq.y);
    float Yx = 0.5f*(Zp.y + Zq.y);
    float Yy = 0.5f*(Zq.x - Zp.x);
    G[gi] = make_float2(Xx*Yx + Xy*Yy, Xx*Yy - Xy*Yx);
  }
  __syncthreads();   // all reads done before any write (p<->q cross-thread)
  #pragma unroll
  for (int gi = 0; gi < VPT; ++gi) z[swz(t + TPB*gi)] = G[gi];
  __syncthreads();

  // ---- inverse DIT FFT: bit-reversed -> natural ----
  dit16(z, t);
  dit_round<16>(z, t);
  dit_round<128>(z, t);
  float re[16];
  float mv = -3.0e38f;
  dit_last(z, t, re, mv);      // corr values stay in registers
  __syncthreads();             // last LDS reads done; z is scratch now

  // ---- argmax: wave max -> block max -> candidate scan in registers ----
  float* zf = (float*)z;
  int*  zi = (int*)z;
  if (t == 0) zi[8] = 0;                        // candidate counter
  #pragma unroll
  for (int off = 32; off > 0; off >>= 1)
    mv = fmaxf(mv, __shfl_down(mv, off));
  const int lane = t & 63, wave = t >> 6;
  if (lane == 0) zf[wave] = mv;                 // zf[0..7]
  __syncthreads();
  float M = zf[0];
  #pragma unroll
  for (int w = 1; w < 8; ++w) M = fmaxf(M, zf[w]);
  // margin 4.0 corr units = 32768 raw (>>100x f32 FFT error bound).
  // Unique candidate within margin => provably the exact (f64) argmax.
  float thresh = M - 32768.0f;
  #pragma unroll
  for (int gi = 0; gi < 2; ++gi)
    #pragma unroll
    for (int k = 0; k < 8; ++k) {
      if (re[8*gi + k] >= thresh) {
        int pos = t + TPB*gi + 1024*k;
        int slot = atomicAdd(&zi[8], 1);
        if (slot < 40) zi[16 + slot] = pos;     // zi[16..55]
      }
    }
  __syncthreads();
  int count = zi[8];
  if (count > 40) count = 40;

  int bestPos;
  if (count == 1) {
    bestPos = zi[16];
  } else {
    // fp64 exact dot for each candidate (np reference FFT is float64)
    double* zd = (double*)z;                    // zd[32..39] = zf[64..79]
    double bestV = -1.0e300;
    int bp = NFFT;
    for (int c = 0; c < count; ++c) {
      int pos = zi[16 + c];
      double part = 0.0;
      #pragma unroll 4
      for (int gi = 0; gi < VPT; ++gi) {
        int n = t + TPB*gi;
        part += (double)xrow[n] * (double)rrow[(n + pos) & (NFFT-1)];
      }
      #pragma unroll
      for (int off = 32; off > 0; off >>= 1)
        part += __shfl_down(part, off);
      if (lane == 0) zd[32 + wave] = part;
      __syncthreads();
      if (t == 0) {
        double tot = 0.0;
        #pragma unroll
        for (int w = 0; w < 8; ++w) tot += zd[32 + w];
        if (tot > bestV || (tot == bestV && pos < bp)) { bestV = tot; bp = pos; }
      }
      __syncthreads();
    }
    if (t == 0) zi[9] = bp;
    __syncthreads();
    bestPos = zi[9];
  }

  // ---- outputs: x_aligned[k] = x[(k - ind) mod N]; inds as float ----
  float* orow = out0 + (size_t)row * NFFT;
  #pragma unroll 4
  for (int gi = 0; gi < VPT; ++gi) {
    int kk = t + TPB*gi;
    orow[kk] = xrow[(kk - bestPos) & (NFFT-1)];
  }
  if (t == 0) outInd[row] = (float)bestPos;
}

extern "C" void kernel_launch(void* const* d_in, const int* in_sizes, int n_in,
                              void* d_out, int out_size, void* d_ws, size_t ws_size,
                              hipStream_t stream) {
  const float* x    = (const float*)d_in[0];
  const float* xref = (const float*)d_in[1];
  float* out = (float*)d_out;
  const int rows = in_sizes[0] / NFFT;   // 32*64 = 2048
  float* outInd = out + (size_t)rows * NFFT;
  hipLaunchKernelGGL(corr_align_kernel, dim3(rows), dim3(TPB), 0, stream,
                     x, xref, out, outInd);
}

// Round 3
// 243.928 us; speedup vs baseline: 1.9439x; 1.2474x over previous
//
#include <hip/hip_runtime.h>
#include <hip/hip_bf16.h>

#define NFFT 8192
#define TPB  512
#define VPT  16   // NFFT / TPB

// XOR swizzle at float2 granularity: spreads all strided FFT access patterns
// across the 32 LDS banks (b64 accesses land 4 lanes/bank-pair = the wave64 floor).
__device__ __forceinline__ int swz(int j) { return j ^ ((j >> 4) & 15); }
__device__ __forceinline__ int rev13(unsigned x) { return (int)(__brev(x) >> 19); }

__device__ __forceinline__ float2 cadd(float2 a, float2 b){ return make_float2(a.x+b.x, a.y+b.y); }
__device__ __forceinline__ float2 csub(float2 a, float2 b){ return make_float2(a.x-b.x, a.y-b.y); }
// d * (c - i s)  (forward twiddle)
__device__ __forceinline__ float2 cmul_conj(float2 d, float c, float s){
  return make_float2(d.x*c + d.y*s, d.y*c - d.x*s);
}
// v * (c + i s)  (inverse twiddle)
__device__ __forceinline__ float2 cmul_pos(float2 v, float c, float s){
  return make_float2(v.x*c - v.y*s, v.y*c + v.x*s);
}

// Twiddles for a fused radix-8 round. One hw sin + one hw cos (input in
// REVOLUTIONS: v_sin_f32 computes sin(2*pi*x)) — no pointer-output lib call.
// alpha = p*pi/(4S); A_k = alpha + k*pi/4; B_k0 = 2a + k0*pi/2; C = 4a.
template<int S>
__device__ __forceinline__ void make_tw(int p, float* cA, float* sA,
                                        float* cB, float* sB, float& c4, float& s4) {
  float r = (float)p * (0.125f / (float)S);   // revolutions: 2*pi*r = p*pi/(4S)
  float sa = __builtin_amdgcn_sinf(r);
  float ca = __builtin_amdgcn_cosf(r);
  float c2 = ca*ca - sa*sa, s2 = 2.0f*ca*sa;
  c4 = c2*c2 - s2*s2; s4 = 2.0f*c2*s2;
  const float R = 0.70710678118654752f;
  cA[0] = ca;          sA[0] = sa;
  cA[1] = R*(ca-sa);   sA[1] = R*(ca+sa);
  cA[2] = -sa;         sA[2] = ca;
  cA[3] = -R*(ca+sa);  sA[3] = R*(ca-sa);
  cB[0] = c2;  sB[0] = s2;
  cB[1] = -s2; sB[1] = c2;
}

// Forward DIF fused radix-8 round: spans 4S,2S,S. 1024 groups, 2 per thread.
template<int S>
__device__ __forceinline__ void dif_round(float2* z, int t) {
  #pragma unroll
  for (int gi = 0; gi < 2; ++gi) {
    int g = t + TPB*gi;
    int p = g & (S-1);
    int blk = g / S;
    int base = blk*(8*S) + p;
    float2 y[8];
    #pragma unroll
    for (int k = 0; k < 8; ++k) y[k] = z[swz(base + k*S)];
    float cA[4], sA[4], cB[2], sB[2], c4, s4;
    make_tw<S>(p, cA, sA, cB, sB, c4, s4);
    #pragma unroll
    for (int k = 0; k < 4; ++k) {
      float2 u = y[k], v = y[k+4];
      y[k] = cadd(u,v);
      y[k+4] = cmul_conj(csub(u,v), cA[k], sA[k]);
    }
    #pragma unroll
    for (int h = 0; h < 8; h += 4)
      #pragma unroll
      for (int k0 = 0; k0 < 2; ++k0) {
        float2 u = y[h+k0], v = y[h+k0+2];
        y[h+k0] = cadd(u,v);
        y[h+k0+2] = cmul_conj(csub(u,v), cB[k0], sB[k0]);
      }
    #pragma unroll
    for (int h = 0; h < 8; h += 2) {
      float2 u = y[h], v = y[h+1];
      y[h] = cadd(u,v);
      y[h+1] = cmul_conj(csub(u,v), c4, s4);
    }
    #pragma unroll
    for (int k = 0; k < 8; ++k) z[swz(base + k*S)] = y[k];
  }
  __syncthreads();
}

// Inverse DIT fused radix-8 round: spans S,2S,4S.
template<int S>
__device__ __forceinline__ void dit_round(float2* z, int t) {
  #pragma unroll
  for (int gi = 0; gi < 2; ++gi) {
    int g = t + TPB*gi;
    int p = g & (S-1);
    int blk = g / S;
    int base = blk*(8*S) + p;
    float2 y[8];
    #pragma unroll
    for (int k = 0; k < 8; ++k) y[k] = z[swz(base + k*S)];
    float cA[4], sA[4], cB[2], sB[2], c4, s4;
    make_tw<S>(p, cA, sA, cB, sB, c4, s4);
    #pragma unroll
    for (int h = 0; h < 8; h += 2) {
      float2 u = y[h];
      float2 w = cmul_pos(y[h+1], c4, s4);
      y[h] = cadd(u,w); y[h+1] = csub(u,w);
    }
    #pragma unroll
    for (int h = 0; h < 8; h += 4)
      #pragma unroll
      for (int k0 = 0; k0 < 2; ++k0) {
        float2 u = y[h+k0];
        float2 w = cmul_pos(y[h+k0+2], cB[k0], sB[k0]);
        y[h+k0] = cadd(u,w); y[h+k0+2] = csub(u,w);
      }
    #pragma unroll
    for (int k = 0; k < 4; ++k) {
      float2 u = y[k];
      float2 w = cmul_pos(y[k+4], cA[k], sA[k]);
      y[k] = cadd(u,w); y[k+4] = csub(u,w);
    }
    #pragma unroll
    for (int k = 0; k < 8; ++k) z[swz(base + k*S)] = y[k];
  }
  __syncthreads();
}

#define C16_1 0.92387953251128674f
#define S16_1 0.38268343236508978f
#define RSQ2  0.70710678118654752f

// Forward radix-16 const-twiddle round: spans 8,4,2,1 on contiguous 16-blocks.
// Angles are j*pi/8 — all compile-time constants, zero transcendentals.
__device__ __forceinline__ void dif16(float2* z, int t) {
  const float C8[8] = {1.f, C16_1, RSQ2, S16_1, 0.f, -S16_1, -RSQ2, -C16_1};
  const float S8[8] = {0.f, S16_1, RSQ2, C16_1, 1.f,  C16_1,  RSQ2,  S16_1};
  float2 y[16];
  int base = 16*t;
  #pragma unroll
  for (int k = 0; k < 16; ++k) y[k] = z[swz(base+k)];
  #pragma unroll
  for (int j = 0; j < 8; ++j) {          // span 8, twiddle W_16^j
    float2 u = y[j], v = y[j+8];
    y[j] = cadd(u,v);
    y[j+8] = cmul_conj(csub(u,v), C8[j], S8[j]);
  }
  #pragma unroll
  for (int h = 0; h < 16; h += 8)        // span 4, twiddle W_8^j
    #pragma unroll
    for (int j = 0; j < 4; ++j) {
      float2 u = y[h+j], v = y[h+j+4];
      y[h+j] = cadd(u,v);
      y[h+j+4] = cmul_conj(csub(u,v), C8[2*j], S8[2*j]);
    }
  #pragma unroll
  for (int h = 0; h < 16; h += 4)        // span 2, twiddle W_4^j (1, -i)
    #pragma unroll
    for (int j = 0; j < 2; ++j) {
      float2 u = y[h+j], v = y[h+j+2];
      y[h+j] = cadd(u,v);
      float2 d = csub(u,v);
      y[h+j+2] = j ? make_float2(d.y, -d.x) : d;
    }
  #pragma unroll
  for (int h = 0; h < 16; h += 2) {      // span 1
    float2 u = y[h], v = y[h+1];
    y[h] = cadd(u,v); y[h+1] = csub(u,v);
  }
  #pragma unroll
  for (int k = 0; k < 16; ++k) z[swz(base+k)] = y[k];
  __syncthreads();
}

// Inverse radix-16 const-twiddle round: spans 1,2,4,8 (conjugate twiddles).
__device__ __forceinline__ void dit16(float2* z, int t) {
  const float C8[8] = {1.f, C16_1, RSQ2, S16_1, 0.f, -S16_1, -RSQ2, -C16_1};
  const float S8[8] = {0.f, S16_1, RSQ2, C16_1, 1.f,  C16_1,  RSQ2,  S16_1};
  float2 y[16];
  int base = 16*t;
  #pragma unroll
  for (int k = 0; k < 16; ++k) y[k] = z[swz(base+k)];
  #pragma unroll
  for (int h = 0; h < 16; h += 2) {      // span 1
    float2 u = y[h], w = y[h+1];
    y[h] = cadd(u,w); y[h+1] = csub(u,w);
  }
  #pragma unroll
  for (int h = 0; h < 16; h += 4)        // span 2, twiddle (1, +i)
    #pragma unroll
    for (int j = 0; j < 2; ++j) {
      float2 u = y[h+j];
      float2 v = y[h+j+2];
      float2 w = j ? make_float2(-v.y, v.x) : v;
      y[h+j] = cadd(u,w); y[h+j+2] = csub(u,w);
    }
  #pragma unroll
  for (int h = 0; h < 16; h += 8)        // span 4
    #pragma unroll
    for (int j = 0; j < 4; ++j) {
      float2 u = y[h+j];
      float2 w = cmul_pos(y[h+j+4], C8[2*j], S8[2*j]);
      y[h+j] = cadd(u,w); y[h+j+4] = csub(u,w);
    }
  #pragma unroll
  for (int j = 0; j < 8; ++j) {          // span 8
    float2 u = y[j];
    float2 w = cmul_pos(y[j+8], C8[j], S8[j]);
    y[j] = cadd(u,w); y[j+8] = csub(u,w);
  }
  #pragma unroll
  for (int k = 0; k < 16; ++k) z[swz(base+k)] = y[k];
  __syncthreads();
}

// Last inverse round (S=1024, spans 1024,2048,4096): keep results in registers,
// fold in the local max. NO LDS write-back, no trailing barrier (caller syncs).
__device__ __forceinline__ void dit_last(const float2* z, int t, float* re, float& mv) {
  #pragma unroll
  for (int gi = 0; gi < 2; ++gi) {
    const int S = 1024;
    int g = t + TPB*gi;          // = p; blk is always 0 (8S == NFFT)
    int base = g;
    float2 y[8];
    #pragma unroll
    for (int k = 0; k < 8; ++k) y[k] = z[swz(base + k*S)];
    float cA[4], sA[4], cB[2], sB[2], c4, s4;
    make_tw<S>(g, cA, sA, cB, sB, c4, s4);
    #pragma unroll
    for (int h = 0; h < 8; h += 2) {
      float2 u = y[h];
      float2 w = cmul_pos(y[h+1], c4, s4);
      y[h] = cadd(u,w); y[h+1] = csub(u,w);
    }
    #pragma unroll
    for (int h = 0; h < 8; h += 4)
      #pragma unroll
      for (int k0 = 0; k0 < 2; ++k0) {
        float2 u = y[h+k0];
        float2 w = cmul_pos(y[h+k0+2], cB[k0], sB[k0]);
        y[h+k0] = cadd(u,w); y[h+k0+2] = csub(u,w);
      }
    #pragma unroll
    for (int k = 0; k < 4; ++k) {
      float2 u = y[k];
      float2 w = cmul_pos(y[k+4], cA[k], sA[k]);
      y[k] = cadd(u,w); y[k+4] = csub(u,w);
    }
    #pragma unroll
    for (int k = 0; k < 8; ++k) {
      re[8*gi + k] = y[k].x;     // corr*N at position g + 1024*k (natural order)
      mv = fmaxf(mv, y[k].x);
    }
  }
}

// NOTE: no waves-per-EU constraint. LDS (64 KiB/block) pins occupancy at
// 2 blocks/CU = 16 waves/CU regardless; constraining VGPRs below that point
// (R2: __launch_bounds__(512,4) -> 64 VGPRs) forced ~400 B/thread of scratch
// spills = +390 MB of HBM writes. Let the allocator breathe.
__global__ __launch_bounds__(TPB)
void corr_align_kernel(const float* __restrict__ x, const float* __restrict__ xref,
                       float* __restrict__ out0, float* __restrict__ outInd) {
  __shared__ float2 z[NFFT];   // exactly 64 KiB -> 2 blocks/CU, 16 waves/CU
  const int t = threadIdx.x;
  const int row = blockIdx.x;
  const float* xrow = x + (size_t)row * NFFT;
  const float* rrow = xref + (size_t)row * NFFT;

  // ---- load: z[n] = x[n] + i*xref[n] ----
  const float4* x4 = (const float4*)xrow;
  const float4* r4 = (const float4*)rrow;
  #pragma unroll
  for (int gi = 0; gi < 4; ++gi) {
    int q = t + TPB*gi;
    float4 xv = x4[q], rv = r4[q];
    int j = 4*q;
    z[swz(j+0)] = make_float2(xv.x, rv.x);
    z[swz(j+1)] = make_float2(xv.y, rv.y);
    z[swz(j+2)] = make_float2(xv.z, rv.z);
    z[swz(j+3)] = make_float2(xv.w, rv.w);
  }
  __syncthreads();

  // ---- forward DIF FFT: natural -> bit-reversed ----
  dif_round<1024>(z, t);
  dif_round<128>(z, t);
  dif_round<16>(z, t);
  dif16(z, t);

  // ---- unpack + cross-spectrum, PAIR-OWNED (no register buffer, no extra
  // barrier): thread owning freq k handles both k and N-k. Each LDS slot is
  // read and written by exactly one thread => no cross-thread hazard.
  // G_{N-k} = conj(G_k) since corr is real.
  #pragma unroll
  for (int gi = 0; gi < 8; ++gi) {
    int k = 8*t + gi + 1;                       // 1..4096
    int p = rev13((unsigned)k);
    int q = rev13((unsigned)((NFFT - k) & (NFFT-1)));
    float2 Zp = z[swz(p)];
    float2 Zq = z[swz(q)];
    float Xx = 0.5f*(Zp.x + Zq.x);
    float Xy = 0.5f*(Zp.y - Zq.y);
    float Yx = 0.5f*(Zp.y + Zq.y);
    float Yy = 0.5f*(Zq.x - Zp.x);
    float2 Gk = make_float2(Xx*Yx + Xy*Yy, Xx*Yy - Xy*Yx);
    z[swz(p)] = Gk;
    if (k != NFFT/2) z[swz(q)] = make_float2(Gk.x, -Gk.y);
  }
  if (t == 0) {
    float2 Z0 = z[0];                           // swz(0)==0; freq 0: X0,Y0 real
    z[0] = make_float2(Z0.x * Z0.y, 0.0f);
  }
  __syncthreads();

  // ---- inverse DIT FFT: bit-reversed -> natural ----
  dit16(z, t);
  dit_round<16>(z, t);
  dit_round<128>(z, t);
  float re[16];
  float mv = -3.0e38f;
  dit_last(z, t, re, mv);      // corr values stay in registers
  __syncthreads();             // last LDS reads done; z is scratch now

  // ---- argmax: wave max -> block max -> candidate scan in registers ----
  float* zf = (float*)z;
  int*  zi = (int*)z;
  if (t == 0) zi[8] = 0;                        // candidate counter
  #pragma unroll
  for (int off = 32; off > 0; off >>= 1)
    mv = fmaxf(mv, __shfl_down(mv, off));
  const int lane = t & 63, wave = t >> 6;
  if (lane == 0) zf[wave] = mv;                 // zf[0..7]
  __syncthreads();
  float M = zf[0];
  #pragma unroll
  for (int w = 1; w < 8; ++w) M = fmaxf(M, zf[w]);
  // margin 4.0 corr units = 32768 raw (>>100x f32 FFT error bound).
  // Unique candidate within margin => provably the exact (f64) argmax.
  float thresh = M - 32768.0f;
  #pragma unroll
  for (int gi = 0; gi < 2; ++gi)
    #pragma unroll
    for (int k = 0; k < 8; ++k) {
      if (re[8*gi + k] >= thresh) {
        int pos = t + TPB*gi + 1024*k;
        int slot = atomicAdd(&zi[8], 1);
        if (slot < 40) zi[16 + slot] = pos;     // zi[16..55]
      }
    }
  __syncthreads();
  int count = zi[8];
  if (count > 40) count = 40;

  int bestPos;
  if (count == 1) {
    bestPos = zi[16];
  } else {
    // fp64 exact dot for each candidate (np reference FFT is float64)
    double* zd = (double*)z;                    // zd[32..39] = bytes 256..320
    double bestV = -1.0e300;
    int bp = NFFT;
    for (int c = 0; c < count; ++c) {
      int pos = zi[16 + c];
      double part = 0.0;
      #pragma unroll 4
      for (int gi = 0; gi < VPT; ++gi) {
        int n = t + TPB*gi;
        part += (double)xrow[n] * (double)rrow[(n + pos) & (NFFT-1)];
      }
      #pragma unroll
      for (int off = 32; off > 0; off >>= 1)
        part += __shfl_down(part, off);
      if (lane == 0) zd[32 + wave] = part;
      __syncthreads();
      if (t == 0) {
        double tot = 0.0;
        #pragma unroll
        for (int w = 0; w < 8; ++w) tot += zd[32 + w];
        if (tot > bestV || (tot == bestV && pos < bp)) { bestV = tot; bp = pos; }
      }
      __syncthreads();
    }
    if (t == 0) zi[9] = bp;
    __syncthreads();
    bestPos = zi[9];
  }

  // ---- outputs: x_aligned[k] = x[(k - ind) mod N]; inds as float ----
  float* orow = out0 + (size_t)row * NFFT;
  #pragma unroll 4
  for (int gi = 0; gi < VPT; ++gi) {
    int kk = t + TPB*gi;
    orow[kk] = xrow[(kk - bestPos) & (NFFT-1)];
  }
  if (t == 0) outInd[row] = (float)bestPos;
}

extern "C" void kernel_launch(void* const* d_in, const int* in_sizes, int n_in,
                              void* d_out, int out_size, void* d_ws, size_t ws_size,
                              hipStream_t stream) {
  const float* x    = (const float*)d_in[0];
  const float* xref = (const float*)d_in[1];
  float* out = (float*)d_out;
  const int rows = in_sizes[0] / NFFT;   // 32*64 = 2048
  float* outInd = out + (size_t)rows * NFFT;
  hipLaunchKernelGGL(corr_align_kernel, dim3(rows), dim3(TPB), 0, stream,
                     x, xref, out, outInd);
}

// Round 4
// 234.660 us; speedup vs baseline: 2.0206x; 1.0395x over previous
//
#include <hip/hip_runtime.h>
#include <hip/hip_bf16.h>

#define NFFT 8192
#define TPB  512
#define VPT  16   // NFFT / TPB

// Native 2-wide float vector => compiler emits v_pk_add_f32 / v_pk_fma_f32
// (packed fp32, 2 FLOP/lane/inst — the only path to the 157 TF vector peak).
typedef float f2 __attribute__((ext_vector_type(2)));

__device__ __forceinline__ f2 mk(float a, float b){ f2 r; r.x=a; r.y=b; return r; }
__device__ __forceinline__ f2 cswap(f2 a){ return __builtin_shufflevector(a,a,1,0); }

// XOR swizzle at f2 granularity: spreads all strided FFT access patterns
// across the 32 LDS banks. Involution (only low 4 bits change).
__device__ __forceinline__ int swz(int j) { return j ^ ((j >> 4) & 15); }
__device__ __forceinline__ int rev13(unsigned x) { return (int)(__brev(x) >> 19); }

// d * (c - i s)  (forward twiddle):  (d.x*c + d.y*s, d.y*c - d.x*s)
__device__ __forceinline__ f2 cmul_conj(f2 d, float c, float s){
  return d*c + cswap(d)*mk(s,-s);        // pk_mul + pk_fma
}
// v * (c + i s)  (inverse twiddle):  (v.x*c - v.y*s, v.y*c + v.x*s)
__device__ __forceinline__ f2 cmul_pos(f2 v, float c, float s){
  return v*c + cswap(v)*mk(-s,s);        // pk_mul + pk_fma
}

// Twiddles for a fused radix-8 round. One hw sin + one hw cos (input in
// REVOLUTIONS: v_sin_f32 computes sin(2*pi*x)) — verified correct in R2/R3.
// alpha = p*pi/(4S); A_k = alpha + k*pi/4; B_k0 = 2a + k0*pi/2; C = 4a.
template<int S>
__device__ __forceinline__ void make_tw(int p, float* cA, float* sA,
                                        float* cB, float* sB, float& c4, float& s4) {
  float r = (float)p * (0.125f / (float)S);
  float sa = __builtin_amdgcn_sinf(r);
  float ca = __builtin_amdgcn_cosf(r);
  float c2 = ca*ca - sa*sa, s2 = 2.0f*ca*sa;
  c4 = c2*c2 - s2*s2; s4 = 2.0f*c2*s2;
  const float R = 0.70710678118654752f;
  cA[0] = ca;          sA[0] = sa;
  cA[1] = R*(ca-sa);   sA[1] = R*(ca+sa);
  cA[2] = -sa;         sA[2] = ca;
  cA[3] = -R*(ca+sa);  sA[3] = R*(ca-sa);
  cB[0] = c2;  sB[0] = s2;
  cB[1] = -s2; sB[1] = c2;
}

// Forward DIF fused radix-8 round: spans 4S,2S,S. 1024 groups, 2 per thread.
template<int S>
__device__ __forceinline__ void dif_round(f2* z, int t) {
  #pragma unroll
  for (int gi = 0; gi < 2; ++gi) {
    int g = t + TPB*gi;
    int p = g & (S-1);
    int blk = g / S;
    int base = blk*(8*S) + p;
    f2 y[8];
    #pragma unroll
    for (int k = 0; k < 8; ++k) y[k] = z[swz(base + k*S)];
    float cA[4], sA[4], cB[2], sB[2], c4, s4;
    make_tw<S>(p, cA, sA, cB, sB, c4, s4);
    #pragma unroll
    for (int k = 0; k < 4; ++k) {
      f2 u = y[k], v = y[k+4];
      y[k] = u + v;
      y[k+4] = cmul_conj(u - v, cA[k], sA[k]);
    }
    #pragma unroll
    for (int h = 0; h < 8; h += 4)
      #pragma unroll
      for (int k0 = 0; k0 < 2; ++k0) {
        f2 u = y[h+k0], v = y[h+k0+2];
        y[h+k0] = u + v;
        y[h+k0+2] = cmul_conj(u - v, cB[k0], sB[k0]);
      }
    #pragma unroll
    for (int h = 0; h < 8; h += 2) {
      f2 u = y[h], v = y[h+1];
      y[h] = u + v;
      y[h+1] = cmul_conj(u - v, c4, s4);
    }
    #pragma unroll
    for (int k = 0; k < 8; ++k) z[swz(base + k*S)] = y[k];
  }
  __syncthreads();
}

// Inverse DIT fused radix-8 round: spans S,2S,4S.
template<int S>
__device__ __forceinline__ void dit_round(f2* z, int t) {
  #pragma unroll
  for (int gi = 0; gi < 2; ++gi) {
    int g = t + TPB*gi;
    int p = g & (S-1);
    int blk = g / S;
    int base = blk*(8*S) + p;
    f2 y[8];
    #pragma unroll
    for (int k = 0; k < 8; ++k) y[k] = z[swz(base + k*S)];
    float cA[4], sA[4], cB[2], sB[2], c4, s4;
    make_tw<S>(p, cA, sA, cB, sB, c4, s4);
    #pragma unroll
    for (int h = 0; h < 8; h += 2) {
      f2 u = y[h];
      f2 w = cmul_pos(y[h+1], c4, s4);
      y[h] = u + w; y[h+1] = u - w;
    }
    #pragma unroll
    for (int h = 0; h < 8; h += 4)
      #pragma unroll
      for (int k0 = 0; k0 < 2; ++k0) {
        f2 u = y[h+k0];
        f2 w = cmul_pos(y[h+k0+2], cB[k0], sB[k0]);
        y[h+k0] = u + w; y[h+k0+2] = u - w;
      }
    #pragma unroll
    for (int k = 0; k < 4; ++k) {
      f2 u = y[k];
      f2 w = cmul_pos(y[k+4], cA[k], sA[k]);
      y[k] = u + w; y[k+4] = u - w;
    }
    #pragma unroll
    for (int k = 0; k < 8; ++k) z[swz(base + k*S)] = y[k];
  }
  __syncthreads();
}

#define C16_1 0.92387953251128674f
#define S16_1 0.38268343236508978f
#define RSQ2  0.70710678118654752f

// Forward radix-16 const-twiddle round: spans 8,4,2,1 on contiguous 16-blocks.
__device__ __forceinline__ void dif16(f2* z, int t) {
  const float C8[8] = {1.f, C16_1, RSQ2, S16_1, 0.f, -S16_1, -RSQ2, -C16_1};
  const float S8[8] = {0.f, S16_1, RSQ2, C16_1, 1.f,  C16_1,  RSQ2,  S16_1};
  f2 y[16];
  int base = 16*t;
  #pragma unroll
  for (int k = 0; k < 16; ++k) y[k] = z[swz(base+k)];
  #pragma unroll
  for (int j = 0; j < 8; ++j) {          // span 8, twiddle W_16^j
    f2 u = y[j], v = y[j+8];
    y[j] = u + v;
    y[j+8] = cmul_conj(u - v, C8[j], S8[j]);
  }
  #pragma unroll
  for (int h = 0; h < 16; h += 8)        // span 4, twiddle W_8^j
    #pragma unroll
    for (int j = 0; j < 4; ++j) {
      f2 u = y[h+j], v = y[h+j+4];
      y[h+j] = u + v;
      y[h+j+4] = cmul_conj(u - v, C8[2*j], S8[2*j]);
    }
  #pragma unroll
  for (int h = 0; h < 16; h += 4)        // span 2, twiddle W_4^j (1, -i)
    #pragma unroll
    for (int j = 0; j < 2; ++j) {
      f2 u = y[h+j], v = y[h+j+2];
      y[h+j] = u + v;
      f2 d = u - v;
      y[h+j+2] = j ? mk(d.y, -d.x) : d;
    }
  #pragma unroll
  for (int h = 0; h < 16; h += 2) {      // span 1
    f2 u = y[h], v = y[h+1];
    y[h] = u + v; y[h+1] = u - v;
  }
  #pragma unroll
  for (int k = 0; k < 16; ++k) z[swz(base+k)] = y[k];
  __syncthreads();
}

// Inverse radix-16 const-twiddle round: spans 1,2,4,8 (conjugate twiddles).
__device__ __forceinline__ void dit16(f2* z, int t) {
  const float C8[8] = {1.f, C16_1, RSQ2, S16_1, 0.f, -S16_1, -RSQ2, -C16_1};
  const float S8[8] = {0.f, S16_1, RSQ2, C16_1, 1.f,  C16_1,  RSQ2,  S16_1};
  f2 y[16];
  int base = 16*t;
  #pragma unroll
  for (int k = 0; k < 16; ++k) y[k] = z[swz(base+k)];
  #pragma unroll
  for (int h = 0; h < 16; h += 2) {      // span 1
    f2 u = y[h], w = y[h+1];
    y[h] = u + w; y[h+1] = u - w;
  }
  #pragma unroll
  for (int h = 0; h < 16; h += 4)        // span 2, twiddle (1, +i)
    #pragma unroll
    for (int j = 0; j < 2; ++j) {
      f2 u = y[h+j];
      f2 v = y[h+j+2];
      f2 w = j ? mk(-v.y, v.x) : v;
      y[h+j] = u + w; y[h+j+2] = u - w;
    }
  #pragma unroll
  for (int h = 0; h < 16; h += 8)        // span 4
    #pragma unroll
    for (int j = 0; j < 4; ++j) {
      f2 u = y[h+j];
      f2 w = cmul_pos(y[h+j+4], C8[2*j], S8[2*j]);
      y[h+j] = u + w; y[h+j+4] = u - w;
    }
  #pragma unroll
  for (int j = 0; j < 8; ++j) {          // span 8
    f2 u = y[j];
    f2 w = cmul_pos(y[j+8], C8[j], S8[j]);
    y[j] = u + w; y[j+8] = u - w;
  }
  #pragma unroll
  for (int k = 0; k < 16; ++k) z[swz(base+k)] = y[k];
  __syncthreads();
}

// Last inverse round (S=1024): results stay in registers + local max.
__device__ __forceinline__ void dit_last(const f2* z, int t, float* re, float& mv) {
  #pragma unroll
  for (int gi = 0; gi < 2; ++gi) {
    const int S = 1024;
    int g = t + TPB*gi;          // = p; blk always 0 (8S == NFFT)
    int base = g;
    f2 y[8];
    #pragma unroll
    for (int k = 0; k < 8; ++k) y[k] = z[swz(base + k*S)];
    float cA[4], sA[4], cB[2], sB[2], c4, s4;
    make_tw<S>(g, cA, sA, cB, sB, c4, s4);
    #pragma unroll
    for (int h = 0; h < 8; h += 2) {
      f2 u = y[h];
      f2 w = cmul_pos(y[h+1], c4, s4);
      y[h] = u + w; y[h+1] = u - w;
    }
    #pragma unroll
    for (int h = 0; h < 8; h += 4)
      #pragma unroll
      for (int k0 = 0; k0 < 2; ++k0) {
        f2 u = y[h+k0];
        f2 w = cmul_pos(y[h+k0+2], cB[k0], sB[k0]);
        y[h+k0] = u + w; y[h+k0+2] = u - w;
      }
    #pragma unroll
    for (int k = 0; k < 4; ++k) {
      f2 u = y[k];
      f2 w = cmul_pos(y[k+4], cA[k], sA[k]);
      y[k] = u + w; y[k+4] = u - w;
    }
    #pragma unroll
    for (int k = 0; k < 8; ++k) {
      re[8*gi + k] = y[k].x;     // corr*N at position g + 1024*k (natural order)
      mv = fmaxf(mv, y[k].x);
    }
  }
}

// No waves-per-EU constraint: LDS (64 KiB/block) pins occupancy at 2 blocks/CU
// = 16 waves/CU; squeezing VGPRs below need (R2) caused 390 MB of spill traffic.
__global__ __launch_bounds__(TPB)
void corr_align_kernel(const float* __restrict__ x, const float* __restrict__ xref,
                       float* __restrict__ out0, float* __restrict__ outInd) {
  __shared__ f2 z[NFFT];   // exactly 64 KiB
  const int t = threadIdx.x;
  const int row = blockIdx.x;
  const float* xrow = x + (size_t)row * NFFT;
  const float* rrow = xref + (size_t)row * NFFT;

  // ---- load: z[n] = x[n] + i*xref[n] ----
  const float4* x4 = (const float4*)xrow;
  const float4* r4 = (const float4*)rrow;
  #pragma unroll
  for (int gi = 0; gi < 4; ++gi) {
    int q = t + TPB*gi;
    float4 xv = x4[q], rv = r4[q];
    int j = 4*q;
    z[swz(j+0)] = mk(xv.x, rv.x);
    z[swz(j+1)] = mk(xv.y, rv.y);
    z[swz(j+2)] = mk(xv.z, rv.z);
    z[swz(j+3)] = mk(xv.w, rv.w);
  }
  __syncthreads();

  // ---- forward DIF FFT: natural -> bit-reversed ----
  dif_round<1024>(z, t);
  dif_round<128>(z, t);
  dif_round<16>(z, t);
  dif16(z, t);

  // ---- unpack + cross-spectrum, PAIR-OWNED (each LDS slot touched by exactly
  // one thread => no hazard, no barrier between read and write).
  // G_{N-k} = conj(G_k) since corr is real.
  #pragma unroll
  for (int gi = 0; gi < 8; ++gi) {
    int k = 8*t + gi + 1;                       // 1..4096
    int p = rev13((unsigned)k);
    int q = rev13((unsigned)((NFFT - k) & (NFFT-1)));
    f2 Zp = z[swz(p)];
    f2 Zq = z[swz(q)];
    float Xx = 0.5f*(Zp.x + Zq.x);
    float Xy = 0.5f*(Zp.y - Zq.y);
    float Yx = 0.5f*(Zp.y + Zq.y);
    float Yy = 0.5f*(Zq.x - Zp.x);
    f2 Gk = mk(Xx*Yx + Xy*Yy, Xx*Yy - Xy*Yx);
    z[swz(p)] = Gk;
    if (k != NFFT/2) z[swz(q)] = mk(Gk.x, -Gk.y);
  }
  if (t == 0) {
    f2 Z0 = z[0];                               // swz(0)==0; freq 0: X0,Y0 real
    z[0] = mk(Z0.x * Z0.y, 0.0f);
  }
  __syncthreads();

  // ---- inverse DIT FFT: bit-reversed -> natural ----
  dit16(z, t);
  dit_round<16>(z, t);
  dit_round<128>(z, t);
  float re[16];
  float mv = -3.0e38f;
  dit_last(z, t, re, mv);      // corr values stay in registers
  __syncthreads();             // last LDS reads done; z is scratch now

  // ---- argmax: wave max -> block max -> candidate scan in registers ----
  float* zf = (float*)z;
  int*  zi = (int*)z;
  if (t == 0) zi[8] = 0;                        // candidate counter
  #pragma unroll
  for (int off = 32; off > 0; off >>= 1)
    mv = fmaxf(mv, __shfl_down(mv, off));
  const int lane = t & 63, wave = t >> 6;
  if (lane == 0) zf[wave] = mv;                 // zf[0..7]
  __syncthreads();
  float M = zf[0];
  #pragma unroll
  for (int w = 1; w < 8; ++w) M = fmaxf(M, zf[w]);
  // margin 4.0 corr units = 32768 raw (>>100x f32 FFT error bound).
  // Unique candidate within margin => provably the exact (f64) argmax.
  float thresh = M - 32768.0f;
  #pragma unroll
  for (int gi = 0; gi < 2; ++gi)
    #pragma unroll
    for (int k = 0; k < 8; ++k) {
      if (re[8*gi + k] >= thresh) {
        int pos = t + TPB*gi + 1024*k;
        int slot = atomicAdd(&zi[8], 1);
        if (slot < 40) zi[16 + slot] = pos;     // zi[16..55]
      }
    }
  __syncthreads();
  int count = zi[8];
  if (count > 40) count = 40;

  int bestPos;
  if (count == 1) {
    bestPos = zi[16];
  } else {
    // fp64 exact dot for each candidate (np reference FFT is float64)
    double* zd = (double*)z;
    double bestV = -1.0e300;
    int bp = NFFT;
    for (int c = 0; c < count; ++c) {
      int pos = zi[16 + c];
      double part = 0.0;
      #pragma unroll 4
      for (int gi = 0; gi < VPT; ++gi) {
        int n = t + TPB*gi;
        part += (double)xrow[n] * (double)rrow[(n + pos) & (NFFT-1)];
      }
      #pragma unroll
      for (int off = 32; off > 0; off >>= 1)
        part += __shfl_down(part, off);
      if (lane == 0) zd[32 + wave] = part;
      __syncthreads();
      if (t == 0) {
        double tot = 0.0;
        #pragma unroll
        for (int w = 0; w < 8; ++w) tot += zd[32 + w];
        if (tot > bestV || (tot == bestV && pos < bp)) { bestV = tot; bp = pos; }
      }
      __syncthreads();
    }
    if (t == 0) zi[9] = bp;
    __syncthreads();
    bestPos = zi[9];
  }

  // ---- outputs: x_aligned[k] = x[(k - ind) mod N]; inds as float ----
  float* orow = out0 + (size_t)row * NFFT;
  #pragma unroll 4
  for (int gi = 0; gi < VPT; ++gi) {
    int kk = t + TPB*gi;
    orow[kk] = xrow[(kk - bestPos) & (NFFT-1)];
  }
  if (t == 0) outInd[row] = (float)bestPos;
}

extern "C" void kernel_launch(void* const* d_in, const int* in_sizes, int n_in,
                              void* d_out, int out_size, void* d_ws, size_t ws_size,
                              hipStream_t stream) {
  const float* x    = (const float*)d_in[0];
  const float* xref = (const float*)d_in[1];
  float* out = (float*)d_out;
  const int rows = in_sizes[0] / NFFT;   // 32*64 = 2048
  float* outInd = out + (size_t)rows * NFFT;
  hipLaunchKernelGGL(corr_align_kernel, dim3(rows), dim3(TPB), 0, stream,
                     x, xref, out, outInd);
}

// Round 5
// 234.019 us; speedup vs baseline: 2.0262x; 1.0027x over previous
//
#include <hip/hip_runtime.h>
#include <hip/hip_bf16.h>

#define NFFT 8192
#define TPB  512
#define VPT  16   // NFFT / TPB

// Wave-internal LDS fence: all this wave's DS writes complete + compiler
// memory fence. Replaces s_barrier for rounds whose data exchange stays
// within one wave's 1024-point chunk (lockstep issue + in-order DS retire).
#define WAVE_FENCE() asm volatile("s_waitcnt lgkmcnt(0)" ::: "memory")

// Native 2-wide float vector => compiler emits v_pk_add_f32 / v_pk_fma_f32.
typedef float f2 __attribute__((ext_vector_type(2)));

__device__ __forceinline__ f2 mk(float a, float b){ f2 r; r.x=a; r.y=b; return r; }
__device__ __forceinline__ f2 cswap(f2 a){ return __builtin_shufflevector(a,a,1,0); }

// XOR swizzle at f2 granularity: spreads strided FFT patterns across 32 banks.
__device__ __forceinline__ int swz(int j) { return j ^ ((j >> 4) & 15); }
__device__ __forceinline__ int rev13(unsigned x) { return (int)(__brev(x) >> 19); }

// d * (c - i s)  (forward twiddle)
__device__ __forceinline__ f2 cmul_conj(f2 d, float c, float s){
  return d*c + cswap(d)*mk(s,-s);
}
// v * (c + i s)  (inverse twiddle)
__device__ __forceinline__ f2 cmul_pos(f2 v, float c, float s){
  return v*c + cswap(v)*mk(-s,s);
}

// Twiddles for a fused radix-8 round; hw sin/cos in revolutions (verified R2-R4).
template<int S>
__device__ __forceinline__ void make_tw(int p, float* cA, float* sA,
                                        float* cB, float* sB, float& c4, float& s4) {
  float r = (float)p * (0.125f / (float)S);
  float sa = __builtin_amdgcn_sinf(r);
  float ca = __builtin_amdgcn_cosf(r);
  float c2 = ca*ca - sa*sa, s2 = 2.0f*ca*sa;
  c4 = c2*c2 - s2*s2; s4 = 2.0f*c2*s2;
  const float R = 0.70710678118654752f;
  cA[0] = ca;          sA[0] = sa;
  cA[1] = R*(ca-sa);   sA[1] = R*(ca+sa);
  cA[2] = -sa;         sA[2] = ca;
  cA[3] = -R*(ca+sa);  sA[3] = R*(ca-sa);
  cB[0] = c2;  sB[0] = s2;
  cB[1] = -s2; sB[1] = c2;
}

// ---- radix-8 butterfly cores (shared by global / wave-local variants) ----
__device__ __forceinline__ void dif8_core(f2* y, int p_num, float inv_den) {
  // twiddle base angle = p_num * (pi/4) / den, passed as p & 1/den pair
  float cA[4], sA[4], cB[2], sB[2], c4, s4;
  {
    float r = (float)p_num * inv_den;
    float sa = __builtin_amdgcn_sinf(r);
    float ca = __builtin_amdgcn_cosf(r);
    float c2 = ca*ca - sa*sa, s2 = 2.0f*ca*sa;
    c4 = c2*c2 - s2*s2; s4 = 2.0f*c2*s2;
    const float R = 0.70710678118654752f;
    cA[0] = ca;          sA[0] = sa;
    cA[1] = R*(ca-sa);   sA[1] = R*(ca+sa);
    cA[2] = -sa;         sA[2] = ca;
    cA[3] = -R*(ca+sa);  sA[3] = R*(ca-sa);
    cB[0] = c2;  sB[0] = s2;
    cB[1] = -s2; sB[1] = c2;
  }
  #pragma unroll
  for (int k = 0; k < 4; ++k) {
    f2 u = y[k], v = y[k+4];
    y[k] = u + v;
    y[k+4] = cmul_conj(u - v, cA[k], sA[k]);
  }
  #pragma unroll
  for (int h = 0; h < 8; h += 4)
    #pragma unroll
    for (int k0 = 0; k0 < 2; ++k0) {
      f2 u = y[h+k0], v = y[h+k0+2];
      y[h+k0] = u + v;
      y[h+k0+2] = cmul_conj(u - v, cB[k0], sB[k0]);
    }
  #pragma unroll
  for (int h = 0; h < 8; h += 2) {
    f2 u = y[h], v = y[h+1];
    y[h] = u + v;
    y[h+1] = cmul_conj(u - v, c4, s4);
  }
}

__device__ __forceinline__ void dit8_core(f2* y, int p_num, float inv_den) {
  float cA[4], sA[4], cB[2], sB[2], c4, s4;
  {
    float r = (float)p_num * inv_den;
    float sa = __builtin_amdgcn_sinf(r);
    float ca = __builtin_amdgcn_cosf(r);
    float c2 = ca*ca - sa*sa, s2 = 2.0f*ca*sa;
    c4 = c2*c2 - s2*s2; s4 = 2.0f*c2*s2;
    const float R = 0.70710678118654752f;
    cA[0] = ca;          sA[0] = sa;
    cA[1] = R*(ca-sa);   sA[1] = R*(ca+sa);
    cA[2] = -sa;         sA[2] = ca;
    cA[3] = -R*(ca+sa);  sA[3] = R*(ca-sa);
    cB[0] = c2;  sB[0] = s2;
    cB[1] = -s2; sB[1] = c2;
  }
  #pragma unroll
  for (int h = 0; h < 8; h += 2) {
    f2 u = y[h];
    f2 w = cmul_pos(y[h+1], c4, s4);
    y[h] = u + w; y[h+1] = u - w;
  }
  #pragma unroll
  for (int h = 0; h < 8; h += 4)
    #pragma unroll
    for (int k0 = 0; k0 < 2; ++k0) {
      f2 u = y[h+k0];
      f2 w = cmul_pos(y[h+k0+2], cB[k0], sB[k0]);
      y[h+k0] = u + w; y[h+k0+2] = u - w;
    }
  #pragma unroll
  for (int k = 0; k < 4; ++k) {
    f2 u = y[k];
    f2 w = cmul_pos(y[k+4], cA[k], sA[k]);
    y[k] = u + w; y[k+4] = u - w;
  }
}

// ---- GLOBAL forward round S=1024 (spans 4096,2048,1024) — needs barrier ----
__device__ __forceinline__ void dif_global1024(f2* z, int t) {
  #pragma unroll
  for (int gi = 0; gi < 2; ++gi) {
    int p = t + TPB*gi;            // 0..1023, blk=0, base=p
    f2 y[8];
    #pragma unroll
    for (int k = 0; k < 8; ++k) y[k] = z[swz(p + k*1024)];
    dif8_core(y, p, 0.125f/1024.0f);
    #pragma unroll
    for (int k = 0; k < 8; ++k) z[swz(p + k*1024)] = y[k];
  }
  __syncthreads();
}

// ---- WAVE-LOCAL radix-8 round (S=128 or 16): chunk = wave's 1024 points ----
template<int S>
__device__ __forceinline__ void dif_wave(f2* z, int w, int l) {
  #pragma unroll
  for (int gi = 0; gi < 2; ++gi) {
    int gl = l + 64*gi;                         // 0..127 within chunk
    int p = gl & (S-1);
    int base = w*1024 + (gl/S)*(8*S) + p;
    f2 y[8];
    #pragma unroll
    for (int k = 0; k < 8; ++k) y[k] = z[swz(base + k*S)];
    dif8_core(y, p, 0.125f/(float)S);
    #pragma unroll
    for (int k = 0; k < 8; ++k) z[swz(base + k*S)] = y[k];
  }
  WAVE_FENCE();
}

template<int S>
__device__ __forceinline__ void dit_wave(f2* z, int w, int l) {
  #pragma unroll
  for (int gi = 0; gi < 2; ++gi) {
    int gl = l + 64*gi;
    int p = gl & (S-1);
    int base = w*1024 + (gl/S)*(8*S) + p;
    f2 y[8];
    #pragma unroll
    for (int k = 0; k < 8; ++k) y[k] = z[swz(base + k*S)];
    dit8_core(y, p, 0.125f/(float)S);
    #pragma unroll
    for (int k = 0; k < 8; ++k) z[swz(base + k*S)] = y[k];
  }
  WAVE_FENCE();
}

#define C16_1 0.92387953251128674f
#define S16_1 0.38268343236508978f
#define RSQ2  0.70710678118654752f

// Forward radix-16 const-twiddle round, wave/thread-local (16 consecutive pts).
__device__ __forceinline__ void dif16_wave(f2* z, int w, int l) {
  const float C8[8] = {1.f, C16_1, RSQ2, S16_1, 0.f, -S16_1, -RSQ2, -C16_1};
  const float S8[8] = {0.f, S16_1, RSQ2, C16_1, 1.f,  C16_1,  RSQ2,  S16_1};
  f2 y[16];
  int base = w*1024 + 16*l;
  #pragma unroll
  for (int k = 0; k < 16; ++k) y[k] = z[swz(base+k)];
  #pragma unroll
  for (int j = 0; j < 8; ++j) {
    f2 u = y[j], v = y[j+8];
    y[j] = u + v;
    y[j+8] = cmul_conj(u - v, C8[j], S8[j]);
  }
  #pragma unroll
  for (int h = 0; h < 16; h += 8)
    #pragma unroll
    for (int j = 0; j < 4; ++j) {
      f2 u = y[h+j], v = y[h+j+4];
      y[h+j] = u + v;
      y[h+j+4] = cmul_conj(u - v, C8[2*j], S8[2*j]);
    }
  #pragma unroll
  for (int h = 0; h < 16; h += 4)
    #pragma unroll
    for (int j = 0; j < 2; ++j) {
      f2 u = y[h+j], v = y[h+j+2];
      y[h+j] = u + v;
      f2 d = u - v;
      y[h+j+2] = j ? mk(d.y, -d.x) : d;
    }
  #pragma unroll
  for (int h = 0; h < 16; h += 2) {
    f2 u = y[h], v = y[h+1];
    y[h] = u + v; y[h+1] = u - v;
  }
  #pragma unroll
  for (int k = 0; k < 16; ++k) z[swz(base+k)] = y[k];
  WAVE_FENCE();
}

// Inverse radix-16 const-twiddle round, thread-local.
__device__ __forceinline__ void dit16_wave(f2* z, int w, int l) {
  const float C8[8] = {1.f, C16_1, RSQ2, S16_1, 0.f, -S16_1, -RSQ2, -C16_1};
  const float S8[8] = {0.f, S16_1, RSQ2, C16_1, 1.f,  C16_1,  RSQ2,  S16_1};
  f2 y[16];
  int base = w*1024 + 16*l;
  #pragma unroll
  for (int k = 0; k < 16; ++k) y[k] = z[swz(base+k)];
  #pragma unroll
  for (int h = 0; h < 16; h += 2) {
    f2 u = y[h], v = y[h+1];
    y[h] = u + v; y[h+1] = u - v;
  }
  #pragma unroll
  for (int h = 0; h < 16; h += 4)
    #pragma unroll
    for (int j = 0; j < 2; ++j) {
      f2 u = y[h+j];
      f2 v = y[h+j+2];
      f2 ww = j ? mk(-v.y, v.x) : v;
      y[h+j] = u + ww; y[h+j+2] = u - ww;
    }
  #pragma unroll
  for (int h = 0; h < 16; h += 8)
    #pragma unroll
    for (int j = 0; j < 4; ++j) {
      f2 u = y[h+j];
      f2 ww = cmul_pos(y[h+j+4], C8[2*j], S8[2*j]);
      y[h+j] = u + ww; y[h+j+4] = u - ww;
    }
  #pragma unroll
  for (int j = 0; j < 8; ++j) {
    f2 u = y[j];
    f2 ww = cmul_pos(y[j+8], C8[j], S8[j]);
    y[j] = u + ww; y[j+8] = u - ww;
  }
  #pragma unroll
  for (int k = 0; k < 16; ++k) z[swz(base+k)] = y[k];
  WAVE_FENCE();
}

// Last inverse round (global, S=1024): results stay in registers + local max.
__device__ __forceinline__ void dit_last(const f2* z, int t, float* re, float& mv) {
  #pragma unroll
  for (int gi = 0; gi < 2; ++gi) {
    int g = t + TPB*gi;
    f2 y[8];
    #pragma unroll
    for (int k = 0; k < 8; ++k) y[k] = z[swz(g + k*1024)];
    dit8_core(y, g, 0.125f/1024.0f);
    #pragma unroll
    for (int k = 0; k < 8; ++k) {
      re[8*gi + k] = y[k].x;     // corr*N at position g + 1024*k
      mv = fmaxf(mv, y[k].x);
    }
  }
}

// No waves-per-EU constraint (R2: VGPR squeeze => 390 MB spill traffic).
__global__ __launch_bounds__(TPB)
void corr_align_kernel(const float* __restrict__ x, const float* __restrict__ xref,
                       float* __restrict__ out0, float* __restrict__ outInd) {
  __shared__ f2 z[NFFT];   // 64 KiB -> 2 blocks/CU
  const int t = threadIdx.x;
  const int lane = t & 63, wave = t >> 6;
  const int row = blockIdx.x;
  const float* xrow = x + (size_t)row * NFFT;
  const float* rrow = xref + (size_t)row * NFFT;

  // ---- load: z[n] = x[n] + i*xref[n] ----
  const float4* x4 = (const float4*)xrow;
  const float4* r4 = (const float4*)rrow;
  #pragma unroll
  for (int gi = 0; gi < 4; ++gi) {
    int q = t + TPB*gi;
    float4 xv = x4[q], rv = r4[q];
    int j = 4*q;
    z[swz(j+0)] = mk(xv.x, rv.x);
    z[swz(j+1)] = mk(xv.y, rv.y);
    z[swz(j+2)] = mk(xv.z, rv.z);
    z[swz(j+3)] = mk(xv.w, rv.w);
  }
  __syncthreads();

  // ---- forward DIF FFT: natural -> bit-reversed ----
  dif_global1024(z, t);          // global mix, barrier inside
  dif_wave<128>(z, wave, lane);  // wave-local: chunk w, fence only
  dif_wave<16>(z, wave, lane);
  dif16_wave(z, wave, lane);
  __syncthreads();               // unpack reads cross-chunk

  // ---- unpack + cross-spectrum, PAIR-OWNED ----
  #pragma unroll
  for (int gi = 0; gi < 8; ++gi) {
    int k = 8*t + gi + 1;                       // 1..4096
    int p = rev13((unsigned)k);
    int q = rev13((unsigned)((NFFT - k) & (NFFT-1)));
    f2 Zp = z[swz(p)];
    f2 Zq = z[swz(q)];
    float Xx = 0.5f*(Zp.x + Zq.x);
    float Xy = 0.5f*(Zp.y - Zq.y);
    float Yx = 0.5f*(Zp.y + Zq.y);
    float Yy = 0.5f*(Zq.x - Zp.x);
    f2 Gk = mk(Xx*Yx + Xy*Yy, Xx*Yy - Xy*Yx);
    z[swz(p)] = Gk;
    if (k != NFFT/2) z[swz(q)] = mk(Gk.x, -Gk.y);
  }
  if (t == 0) {
    f2 Z0 = z[0];
    z[0] = mk(Z0.x * Z0.y, 0.0f);
  }
  __syncthreads();

  // ---- inverse DIT FFT: bit-reversed -> natural ----
  dit16_wave(z, wave, lane);
  dit_wave<16>(z, wave, lane);
  dit_wave<128>(z, wave, lane);
  __syncthreads();               // last round reads cross-chunk
  float re[16];
  float mv = -3.0e38f;
  dit_last(z, t, re, mv);        // corr values stay in registers
  __syncthreads();               // z becomes argmax scratch

  // ---- argmax: wave max -> block max -> candidate scan in registers ----
  float* zf = (float*)z;
  int*  zi = (int*)z;
  if (t == 0) zi[8] = 0;
  #pragma unroll
  for (int off = 32; off > 0; off >>= 1)
    mv = fmaxf(mv, __shfl_down(mv, off));
  if (lane == 0) zf[wave] = mv;
  __syncthreads();
  float M = zf[0];
  #pragma unroll
  for (int w = 1; w < 8; ++w) M = fmaxf(M, zf[w]);
  // margin 4.0 corr units = 32768 raw (>>100x f32 FFT error bound).
  float thresh = M - 32768.0f;
  #pragma unroll
  for (int gi = 0; gi < 2; ++gi)
    #pragma unroll
    for (int k = 0; k < 8; ++k) {
      if (re[8*gi + k] >= thresh) {
        int pos = t + TPB*gi + 1024*k;
        int slot = atomicAdd(&zi[8], 1);
        if (slot < 40) zi[16 + slot] = pos;
      }
    }
  __syncthreads();
  int count = zi[8];
  if (count > 40) count = 40;

  int bestPos;
  if (count == 1) {
    bestPos = zi[16];
  } else {
    // fp64 exact dot per candidate (np reference FFT is float64)
    double* zd = (double*)z;
    double bestV = -1.0e300;
    int bp = NFFT;
    for (int c = 0; c < count; ++c) {
      int pos = zi[16 + c];
      double part = 0.0;
      #pragma unroll 4
      for (int gi = 0; gi < VPT; ++gi) {
        int n = t + TPB*gi;
        part += (double)xrow[n] * (double)rrow[(n + pos) & (NFFT-1)];
      }
      #pragma unroll
      for (int off = 32; off > 0; off >>= 1)
        part += __shfl_down(part, off);
      if (lane == 0) zd[32 + wave] = part;
      __syncthreads();
      if (t == 0) {
        double tot = 0.0;
        #pragma unroll
        for (int w = 0; w < 8; ++w) tot += zd[32 + w];
        if (tot > bestV || (tot == bestV && pos < bp)) { bestV = tot; bp = pos; }
      }
      __syncthreads();
    }
    if (t == 0) zi[9] = bp;
    __syncthreads();
    bestPos = zi[9];
  }

  // ---- outputs: x_aligned[k] = x[(k - ind) mod N]; inds as float ----
  float* orow = out0 + (size_t)row * NFFT;
  #pragma unroll 4
  for (int gi = 0; gi < VPT; ++gi) {
    int kk = t + TPB*gi;
    orow[kk] = xrow[(kk - bestPos) & (NFFT-1)];
  }
  if (t == 0) outInd[row] = (float)bestPos;
}

extern "C" void kernel_launch(void* const* d_in, const int* in_sizes, int n_in,
                              void* d_out, int out_size, void* d_ws, size_t ws_size,
                              hipStream_t stream) {
  const float* x    = (const float*)d_in[0];
  const float* xref = (const float*)d_in[1];
  float* out = (float*)d_out;
  const int rows = in_sizes[0] / NFFT;   // 32*64 = 2048
  float* outInd = out + (size_t)rows * NFFT;
  hipLaunchKernelGGL(corr_align_kernel, dim3(rows), dim3(TPB), 0, stream,
                     x, xref, out, outInd);
}

// Round 6
// 228.683 us; speedup vs baseline: 2.0735x; 1.0233x over previous
//
#include <hip/hip_runtime.h>
#include <hip/hip_bf16.h>

#define NFFT 8192
#define TPB  512
#define VPT  16   // NFFT / TPB

// Native 2-wide float vector => compiler emits v_pk_add_f32 / v_pk_fma_f32.
typedef float f2 __attribute__((ext_vector_type(2)));

__device__ __forceinline__ f2 mk(float a, float b){ f2 r; r.x=a; r.y=b; return r; }
__device__ __forceinline__ f2 cswap(f2 a){ return __builtin_shufflevector(a,a,1,0); }

// XOR swizzle at f2 granularity (physical layout identical to R4/R5).
// Rounds below use closed-form identities so swz costs 0-2 VALU per access:
//   swz(p + 1024k) = swz(p) + 1024k
//   swz(b + 128k)  = (swz(b) ^ 8(k&1)) + 128k
//   swz(b + 16k)   = (b&~15) + 16k + ((b&15) ^ 8(blk&1) ^ k)
//   swz(16t + c)   = 16t + (c ^ (t&15))
__device__ __forceinline__ int swz(int j) { return j ^ ((j >> 4) & 15); }
__device__ __forceinline__ int rev13(unsigned x) { return (int)(__brev(x) >> 19); }

// d * (c - i s)  (forward twiddle)
__device__ __forceinline__ f2 cmul_conj(f2 d, float c, float s){
  return d*c + cswap(d)*mk(s,-s);
}
// v * (c + i s)  (inverse twiddle)
__device__ __forceinline__ f2 cmul_pos(f2 v, float c, float s){
  return v*c + cswap(v)*mk(-s,s);
}

// ---- radix-8 butterfly cores; hw sin/cos in revolutions (verified R2-R5) ----
__device__ __forceinline__ void dif8_core(f2* y, int p_num, float inv_den) {
  float cA[4], sA[4], cB[2], sB[2], c4, s4;
  {
    float r = (float)p_num * inv_den;
    float sa = __builtin_amdgcn_sinf(r);
    float ca = __builtin_amdgcn_cosf(r);
    float c2 = ca*ca - sa*sa, s2 = 2.0f*ca*sa;
    c4 = c2*c2 - s2*s2; s4 = 2.0f*c2*s2;
    const float R = 0.70710678118654752f;
    cA[0] = ca;          sA[0] = sa;
    cA[1] = R*(ca-sa);   sA[1] = R*(ca+sa);
    cA[2] = -sa;         sA[2] = ca;
    cA[3] = -R*(ca+sa);  sA[3] = R*(ca-sa);
    cB[0] = c2;  sB[0] = s2;
    cB[1] = -s2; sB[1] = c2;
  }
  #pragma unroll
  for (int k = 0; k < 4; ++k) {
    f2 u = y[k], v = y[k+4];
    y[k] = u + v;
    y[k+4] = cmul_conj(u - v, cA[k], sA[k]);
  }
  #pragma unroll
  for (int h = 0; h < 8; h += 4)
    #pragma unroll
    for (int k0 = 0; k0 < 2; ++k0) {
      f2 u = y[h+k0], v = y[h+k0+2];
      y[h+k0] = u + v;
      y[h+k0+2] = cmul_conj(u - v, cB[k0], sB[k0]);
    }
  #pragma unroll
  for (int h = 0; h < 8; h += 2) {
    f2 u = y[h], v = y[h+1];
    y[h] = u + v;
    y[h+1] = cmul_conj(u - v, c4, s4);
  }
}

__device__ __forceinline__ void dit8_core(f2* y, int p_num, float inv_den) {
  float cA[4], sA[4], cB[2], sB[2], c4, s4;
  {
    float r = (float)p_num * inv_den;
    float sa = __builtin_amdgcn_sinf(r);
    float ca = __builtin_amdgcn_cosf(r);
    float c2 = ca*ca - sa*sa, s2 = 2.0f*ca*sa;
    c4 = c2*c2 - s2*s2; s4 = 2.0f*c2*s2;
    const float R = 0.70710678118654752f;
    cA[0] = ca;          sA[0] = sa;
    cA[1] = R*(ca-sa);   sA[1] = R*(ca+sa);
    cA[2] = -sa;         sA[2] = ca;
    cA[3] = -R*(ca+sa);  sA[3] = R*(ca-sa);
    cB[0] = c2;  sB[0] = s2;
    cB[1] = -s2; sB[1] = c2;
  }
  #pragma unroll
  for (int h = 0; h < 8; h += 2) {
    f2 u = y[h];
    f2 w = cmul_pos(y[h+1], c4, s4);
    y[h] = u + w; y[h+1] = u - w;
  }
  #pragma unroll
  for (int h = 0; h < 8; h += 4)
    #pragma unroll
    for (int k0 = 0; k0 < 2; ++k0) {
      f2 u = y[h+k0];
      f2 w = cmul_pos(y[h+k0+2], cB[k0], sB[k0]);
      y[h+k0] = u + w; y[h+k0+2] = u - w;
    }
  #pragma unroll
  for (int k = 0; k < 4; ++k) {
    f2 u = y[k];
    f2 w = cmul_pos(y[k+4], cA[k], sA[k]);
    y[k] = u + w; y[k+4] = u - w;
  }
}

// ---- GLOBAL forward round S=1024: swz(p+1024k) = swz(p)+1024k -> imm offsets
__device__ __forceinline__ void dif_global1024(f2* z, int t) {
  #pragma unroll
  for (int gi = 0; gi < 2; ++gi) {
    int p = t + TPB*gi;
    f2* B = z + swz(p);
    f2 y[8];
    #pragma unroll
    for (int k = 0; k < 8; ++k) y[k] = B[1024*k];
    dif8_core(y, p, 0.125f/1024.0f);
    #pragma unroll
    for (int k = 0; k < 8; ++k) B[1024*k] = y[k];
  }
  __syncthreads();
}

// ---- WAVE-LOCAL S=128: two bases (swz(b), swz(b)^8) + imm offsets.
// No fence: a wave's DS ops retire in order (lgkmcnt in-order for LDS),
// so own-wave read-after-write across rounds is safe and pipelines.
__device__ __forceinline__ void dif_wave128(f2* z, int w, int l) {
  #pragma unroll
  for (int gi = 0; gi < 2; ++gi) {
    int gl = l + 64*gi;
    int E = swz(w*1024 + gl);
    f2* B0 = z + E;
    f2* B1 = z + (E ^ 8);
    f2 y[8];
    #pragma unroll
    for (int k = 0; k < 8; ++k) y[k] = (k&1) ? B1[128*k] : B0[128*k];
    dif8_core(y, gl, 0.125f/128.0f);
    #pragma unroll
    for (int k = 0; k < 8; ++k) { if (k&1) B1[128*k] = y[k]; else B0[128*k] = y[k]; }
  }
}

__device__ __forceinline__ void dit_wave128(f2* z, int w, int l) {
  #pragma unroll
  for (int gi = 0; gi < 2; ++gi) {
    int gl = l + 64*gi;
    int E = swz(w*1024 + gl);
    f2* B0 = z + E;
    f2* B1 = z + (E ^ 8);
    f2 y[8];
    #pragma unroll
    for (int k = 0; k < 8; ++k) y[k] = (k&1) ? B1[128*k] : B0[128*k];
    dit8_core(y, gl, 0.125f/128.0f);
    #pragma unroll
    for (int k = 0; k < 8; ++k) { if (k&1) B1[128*k] = y[k]; else B0[128*k] = y[k]; }
  }
}

// ---- WAVE-LOCAL S=16: swz(b+16k) = H + 16k + (e^k), e = p ^ 8(blk&1)
__device__ __forceinline__ void dif_wave16(f2* z, int w, int l) {
  #pragma unroll
  for (int gi = 0; gi < 2; ++gi) {
    int gl = l + 64*gi;
    int p = gl & 15, blk = gl >> 4;
    int e = p ^ (8*(blk&1));
    f2* H = z + (w*1024 + blk*128);
    f2 y[8];
    #pragma unroll
    for (int k = 0; k < 8; ++k) y[k] = H[16*k + (e ^ k)];
    dif8_core(y, p, 0.125f/16.0f);
    #pragma unroll
    for (int k = 0; k < 8; ++k) H[16*k + (e ^ k)] = y[k];
  }
}

__device__ __forceinline__ void dit_wave16(f2* z, int w, int l) {
  #pragma unroll
  for (int gi = 0; gi < 2; ++gi) {
    int gl = l + 64*gi;
    int p = gl & 15, blk = gl >> 4;
    int e = p ^ (8*(blk&1));
    f2* H = z + (w*1024 + blk*128);
    f2 y[8];
    #pragma unroll
    for (int k = 0; k < 8; ++k) y[k] = H[16*k + (e ^ k)];
    dit8_core(y, p, 0.125f/16.0f);
    #pragma unroll
    for (int k = 0; k < 8; ++k) H[16*k + (e ^ k)] = y[k];
  }
}

#define C16_1 0.92387953251128674f
#define S16_1 0.38268343236508978f
#define RSQ2  0.70710678118654752f

// ---- radix-16 const-twiddle rounds: swz(16t+c) = 16t + (c ^ (t&15))
__device__ __forceinline__ void dif16_x(f2* z, int t) {
  const float C8[8] = {1.f, C16_1, RSQ2, S16_1, 0.f, -S16_1, -RSQ2, -C16_1};
  const float S8[8] = {0.f, S16_1, RSQ2, C16_1, 1.f,  C16_1,  RSQ2,  S16_1};
  int e = t & 15;
  f2* H = z + 16*t;
  f2 y[16];
  #pragma unroll
  for (int c = 0; c < 16; ++c) y[c] = H[c ^ e];
  #pragma unroll
  for (int j = 0; j < 8; ++j) {
    f2 u = y[j], v = y[j+8];
    y[j] = u + v;
    y[j+8] = cmul_conj(u - v, C8[j], S8[j]);
  }
  #pragma unroll
  for (int h = 0; h < 16; h += 8)
    #pragma unroll
    for (int j = 0; j < 4; ++j) {
      f2 u = y[h+j], v = y[h+j+4];
      y[h+j] = u + v;
      y[h+j+4] = cmul_conj(u - v, C8[2*j], S8[2*j]);
    }
  #pragma unroll
  for (int h = 0; h < 16; h += 4)
    #pragma unroll
    for (int j = 0; j < 2; ++j) {
      f2 u = y[h+j], v = y[h+j+2];
      y[h+j] = u + v;
      f2 d = u - v;
      y[h+j+2] = j ? mk(d.y, -d.x) : d;
    }
  #pragma unroll
  for (int h = 0; h < 16; h += 2) {
    f2 u = y[h], v = y[h+1];
    y[h] = u + v; y[h+1] = u - v;
  }
  #pragma unroll
  for (int c = 0; c < 16; ++c) H[c ^ e] = y[c];
}

__device__ __forceinline__ void dit16_x(f2* z, int t) {
  const float C8[8] = {1.f, C16_1, RSQ2, S16_1, 0.f, -S16_1, -RSQ2, -C16_1};
  const float S8[8] = {0.f, S16_1, RSQ2, C16_1, 1.f,  C16_1,  RSQ2,  S16_1};
  int e = t & 15;
  f2* H = z + 16*t;
  f2 y[16];
  #pragma unroll
  for (int c = 0; c < 16; ++c) y[c] = H[c ^ e];
  #pragma unroll
  for (int h = 0; h < 16; h += 2) {
    f2 u = y[h], v = y[h+1];
    y[h] = u + v; y[h+1] = u - v;
  }
  #pragma unroll
  for (int h = 0; h < 16; h += 4)
    #pragma unroll
    for (int j = 0; j < 2; ++j) {
      f2 u = y[h+j];
      f2 v = y[h+j+2];
      f2 w = j ? mk(-v.y, v.x) : v;
      y[h+j] = u + w; y[h+j+2] = u - w;
    }
  #pragma unroll
  for (int h = 0; h < 16; h += 8)
    #pragma unroll
    for (int j = 0; j < 4; ++j) {
      f2 u = y[h+j];
      f2 w = cmul_pos(y[h+j+4], C8[2*j], S8[2*j]);
      y[h+j] = u + w; y[h+j+4] = u - w;
    }
  #pragma unroll
  for (int j = 0; j < 8; ++j) {
    f2 u = y[j];
    f2 w = cmul_pos(y[j+8], C8[j], S8[j]);
    y[j] = u + w; y[j+8] = u - w;
  }
  #pragma unroll
  for (int c = 0; c < 16; ++c) H[c ^ e] = y[c];
}

// Last inverse round (global S=1024): imm offsets; results stay in registers.
__device__ __forceinline__ void dit_last(const f2* z, int t, float* re, float& mv) {
  #pragma unroll
  for (int gi = 0; gi < 2; ++gi) {
    int g = t + TPB*gi;
    const f2* B = z + swz(g);
    f2 y[8];
    #pragma unroll
    for (int k = 0; k < 8; ++k) y[k] = B[1024*k];
    dit8_core(y, g, 0.125f/1024.0f);
    #pragma unroll
    for (int k = 0; k < 8; ++k) {
      re[8*gi + k] = y[k].x;     // corr*N at position g + 1024*k
      mv = fmaxf(mv, y[k].x);
    }
  }
}

// No waves-per-EU constraint (R2: VGPR squeeze => 390 MB spill traffic).
__global__ __launch_bounds__(TPB)
void corr_align_kernel(const float* __restrict__ x, const float* __restrict__ xref,
                       float* __restrict__ out0, float* __restrict__ outInd) {
  __shared__ f2 z[NFFT];   // 64 KiB
  const int t = threadIdx.x;
  const int lane = t & 63, wave = t >> 6;
  const int row = blockIdx.x;
  const float* xrow = x + (size_t)row * NFFT;
  const float* rrow = xref + (size_t)row * NFFT;

  // ---- load: z[n] = x[n] + i*xref[n] ----
  const float4* x4 = (const float4*)xrow;
  const float4* r4 = (const float4*)rrow;
  #pragma unroll
  for (int gi = 0; gi < 4; ++gi) {
    int q = t + TPB*gi;
    float4 xv = x4[q], rv = r4[q];
    int j = 4*q;
    z[swz(j+0)] = mk(xv.x, rv.x);
    z[swz(j+1)] = mk(xv.y, rv.y);
    z[swz(j+2)] = mk(xv.z, rv.z);
    z[swz(j+3)] = mk(xv.w, rv.w);
  }
  __syncthreads();

  // ---- forward DIF FFT: natural -> bit-reversed ----
  dif_global1024(z, t);          // cross-wave, barrier inside
  dif_wave128(z, wave, lane);    // wave-local: own-chunk, DS-order safe
  dif_wave16(z, wave, lane);
  dif16_x(z, t);
  __syncthreads();               // unpack reads cross-chunk

  // ---- unpack + cross-spectrum, PAIR-OWNED ----
  #pragma unroll
  for (int gi = 0; gi < 8; ++gi) {
    int k = 8*t + gi + 1;                       // 1..4096
    int p = rev13((unsigned)k);
    int q = rev13((unsigned)((NFFT - k) & (NFFT-1)));
    f2 Zp = z[swz(p)];
    f2 Zq = z[swz(q)];
    float Xx = 0.5f*(Zp.x + Zq.x);
    float Xy = 0.5f*(Zp.y - Zq.y);
    float Yx = 0.5f*(Zp.y + Zq.y);
    float Yy = 0.5f*(Zq.x - Zp.x);
    f2 Gk = mk(Xx*Yx + Xy*Yy, Xx*Yy - Xy*Yx);
    z[swz(p)] = Gk;
    if (k != NFFT/2) z[swz(q)] = mk(Gk.x, -Gk.y);
  }
  if (t == 0) {
    f2 Z0 = z[0];
    z[0] = mk(Z0.x * Z0.y, 0.0f);
  }
  __syncthreads();

  // ---- inverse DIT FFT: bit-reversed -> natural ----
  dit16_x(z, t);
  dit_wave16(z, wave, lane);
  dit_wave128(z, wave, lane);
  __syncthreads();               // last round reads cross-chunk
  float re[16];
  float mv = -3.0e38f;
  dit_last(z, t, re, mv);        // corr values stay in registers
  __syncthreads();               // z becomes argmax scratch

  // ---- argmax: wave max -> block max -> candidate scan in registers ----
  float* zf = (float*)z;
  int*  zi = (int*)z;
  if (t == 0) zi[8] = 0;
  #pragma unroll
  for (int off = 32; off > 0; off >>= 1)
    mv = fmaxf(mv, __shfl_down(mv, off));
  if (lane == 0) zf[wave] = mv;
  __syncthreads();
  float M = zf[0];
  #pragma unroll
  for (int w = 1; w < 8; ++w) M = fmaxf(M, zf[w]);
  // margin 4.0 corr units = 32768 raw (>>100x f32 FFT error bound).
  float thresh = M - 32768.0f;
  #pragma unroll
  for (int gi = 0; gi < 2; ++gi)
    #pragma unroll
    for (int k = 0; k < 8; ++k) {
      if (re[8*gi + k] >= thresh) {
        int pos = t + TPB*gi + 1024*k;
        int slot = atomicAdd(&zi[8], 1);
        if (slot < 40) zi[16 + slot] = pos;
      }
    }
  __syncthreads();
  int count = zi[8];
  if (count > 40) count = 40;

  int bestPos;
  if (count == 1) {
    bestPos = zi[16];
  } else {
    // fp64 exact dot per candidate (np reference FFT is float64)
    double* zd = (double*)z;
    double bestV = -1.0e300;
    int bp = NFFT;
    for (int c = 0; c < count; ++c) {
      int pos = zi[16 + c];
      double part = 0.0;
      #pragma unroll 4
      for (int gi = 0; gi < VPT; ++gi) {
        int n = t + TPB*gi;
        part += (double)xrow[n] * (double)rrow[(n + pos) & (NFFT-1)];
      }
      #pragma unroll
      for (int off = 32; off > 0; off >>= 1)
        part += __shfl_down(part, off);
      if (lane == 0) zd[32 + wave] = part;
      __syncthreads();
      if (t == 0) {
        double tot = 0.0;
        #pragma unroll
        for (int w = 0; w < 8; ++w) tot += zd[32 + w];
        if (tot > bestV || (tot == bestV && pos < bp)) { bestV = tot; bp = pos; }
      }
      __syncthreads();
    }
    if (t == 0) zi[9] = bp;
    __syncthreads();
    bestPos = zi[9];
  }

  // ---- outputs: x_aligned[k] = x[(k - ind) mod N]; inds as float ----
  float* orow = out0 + (size_t)row * NFFT;
  #pragma unroll 4
  for (int gi = 0; gi < VPT; ++gi) {
    int kk = t + TPB*gi;
    orow[kk] = xrow[(kk - bestPos) & (NFFT-1)];
  }
  if (t == 0) outInd[row] = (float)bestPos;
}

extern "C" void kernel_launch(void* const* d_in, const int* in_sizes, int n_in,
                              void* d_out, int out_size, void* d_ws, size_t ws_size,
                              hipStream_t stream) {
  const float* x    = (const float*)d_in[0];
  const float* xref = (const float*)d_in[1];
  float* out = (float*)d_out;
  const int rows = in_sizes[0] / NFFT;   // 32*64 = 2048
  float* outInd = out + (size_t)rows * NFFT;
  hipLaunchKernelGGL(corr_align_kernel, dim3(rows), dim3(TPB), 0, stream,
                     x, xref, out, outInd);
}